// Round 7
// baseline (192.956 us; speedup 1.0000x reference)
//
#include <hip/hip_runtime.h>

// ---------------------------------------------------------------------------
// TransformerBlock: LN1 -> QKV -> attn(+bias, softmax) -> Wo(+x) -> LN2
//                   -> FFN1(+mish) -> FFN2(+residual)
// fp32 I/O, bf16 MFMA GEMMs (16x16x32), flash-style attention.
// R7: 3-stage counted-vmcnt GEMM pipeline (vmcnt(4), single barrier/step),
//     QKV at 64x64 (clean 2-round grid), FFN1 at 128x128 8-wave,
//     LN1 fused into convert kernel.
// ---------------------------------------------------------------------------

typedef __attribute__((ext_vector_type(8))) __bf16 bf16x8;
typedef __attribute__((ext_vector_type(4))) float  f32x4;

__device__ __forceinline__ unsigned short f2bf(float f) {
  unsigned int u = __builtin_bit_cast(unsigned int, f);
  u += 0x7fffu + ((u >> 16) & 1u);          // round-to-nearest-even
  return (unsigned short)(u >> 16);
}

__device__ __forceinline__ void gload16(const void* g, void* l) {
  __builtin_amdgcn_global_load_lds(
      (const __attribute__((address_space(1))) void*)g,
      (__attribute__((address_space(3))) void*)l, 16, 0, 0);
}

// ---------------------------------------------------------------------------
// Fused: 4 weight converts fp32(KxN)->bf16 transposed(NxK)  +  LN1.
// blocks 0..12287: converts; 12288..14335: LN1 rows.
// ---------------------------------------------------------------------------
__global__ __launch_bounds__(256) void convert_ln(
    const float* __restrict__ Wqkv, const float* __restrict__ Wo,
    const float* __restrict__ W1, const float* __restrict__ W2,
    const float* __restrict__ x, const float* __restrict__ g,
    const float* __restrict__ bln,
    unsigned short* __restrict__ wqkv_t, unsigned short* __restrict__ wo_t,
    unsigned short* __restrict__ w1_t, unsigned short* __restrict__ w2_t,
    unsigned short* __restrict__ h1) {
  __shared__ float tile[32][33];
  __shared__ float ps[4], ps2[4];
  const int id = blockIdx.x;
  const int tx = threadIdx.x, ty = threadIdx.y;   // (32,8)

  if (id < 12288) {
    const float* W; unsigned short* Wt; int K, N, t;
    if (id < 3072)      { W = Wqkv; Wt = wqkv_t; K = 1024; N = 3072; t = id; }
    else if (id < 4096) { W = Wo;   Wt = wo_t;   K = 1024; N = 1024; t = id - 3072; }
    else if (id < 8192) { W = W1;   Wt = w1_t;   K = 1024; N = 4096; t = id - 4096; }
    else                { W = W2;   Wt = w2_t;   K = 4096; N = 1024; t = id - 8192; }
    const int nx = N >> 5;
    const int n0 = (t % nx) * 32, k0 = (t / nx) * 32;
#pragma unroll
    for (int r = 0; r < 4; ++r)
      tile[ty + 8 * r][tx] = W[(size_t)(k0 + ty + 8 * r) * N + n0 + tx];
    __syncthreads();
#pragma unroll
    for (int r = 0; r < 4; ++r)
      Wt[(size_t)(n0 + ty + 8 * r) * K + k0 + tx] = f2bf(tile[tx][ty + 8 * r]);
  } else {
    const int row = id - 12288;
    const int t = ty * 32 + tx;
    const float4 v = reinterpret_cast<const float4*>(x + (size_t)row * 1024)[t];
    float s  = v.x + v.y + v.z + v.w;
    float s2 = v.x * v.x + v.y * v.y + v.z * v.z + v.w * v.w;
#pragma unroll
    for (int m = 1; m < 64; m <<= 1) { s += __shfl_xor(s, m); s2 += __shfl_xor(s2, m); }
    const int wv = t >> 6;
    if ((t & 63) == 0) { ps[wv] = s; ps2[wv] = s2; }
    __syncthreads();
    float ts = 0.f, ts2 = 0.f;
#pragma unroll
    for (int i = 0; i < 4; ++i) { ts += ps[i]; ts2 += ps2[i]; }
    const float mu = ts * (1.f / 1024.f);
    const float var = ts2 * (1.f / 1024.f) - mu * mu;
    const float rstd = rsqrtf(var + 1e-5f);
    const float4 gg = reinterpret_cast<const float4*>(g)[t];
    const float4 bb = reinterpret_cast<const float4*>(bln)[t];
    ushort4 ov;
    ov.x = f2bf((v.x - mu) * rstd * gg.x + bb.x);
    ov.y = f2bf((v.y - mu) * rstd * gg.y + bb.y);
    ov.z = f2bf((v.z - mu) * rstd * gg.z + bb.z);
    ov.w = f2bf((v.w - mu) * rstd * gg.w + bb.w);
    *reinterpret_cast<ushort4*>(h1 + (size_t)row * 1024 + t * 4) = ov;
  }
}

// ---------------------------------------------------------------------------
// LayerNorm (standalone, for LN2).
// ---------------------------------------------------------------------------
__global__ __launch_bounds__(256) void ln_kernel(const float* __restrict__ in,
                                                 const float* __restrict__ g,
                                                 const float* __restrict__ b,
                                                 unsigned short* __restrict__ out) {
  const int row = blockIdx.x;
  const int t = threadIdx.x;
  const float4 v = reinterpret_cast<const float4*>(in + (size_t)row * 1024)[t];
  float s  = v.x + v.y + v.z + v.w;
  float s2 = v.x * v.x + v.y * v.y + v.z * v.z + v.w * v.w;
#pragma unroll
  for (int m = 1; m < 64; m <<= 1) { s += __shfl_xor(s, m); s2 += __shfl_xor(s2, m); }
  __shared__ float ps[4], ps2[4];
  const int wv = t >> 6;
  if ((t & 63) == 0) { ps[wv] = s; ps2[wv] = s2; }
  __syncthreads();
  float ts = 0.f, ts2 = 0.f;
#pragma unroll
  for (int i = 0; i < 4; ++i) { ts += ps[i]; ts2 += ps2[i]; }
  const float mu = ts * (1.f / 1024.f);
  const float var = ts2 * (1.f / 1024.f) - mu * mu;
  const float rstd = rsqrtf(var + 1e-5f);
  const float4 gg = reinterpret_cast<const float4*>(g)[t];
  const float4 bb = reinterpret_cast<const float4*>(b)[t];
  ushort4 ov;
  ov.x = f2bf((v.x - mu) * rstd * gg.x + bb.x);
  ov.y = f2bf((v.y - mu) * rstd * gg.y + bb.y);
  ov.z = f2bf((v.z - mu) * rstd * gg.z + bb.z);
  ov.w = f2bf((v.w - mu) * rstd * gg.w + bb.w);
  *reinterpret_cast<ushort4*>(out + (size_t)row * 1024 + t * 4) = ov;
}

// ---------------------------------------------------------------------------
// GEMM: C(MxN) = A(MxK bf16 row-major) @ Bt(NxK bf16 row-major)^T + bias
// 3-stage pipeline, counted vmcnt(4), one barrier per K-step.
// BM=BN=64: 4 waves (2x2, 32x32/wave), 48KB LDS, 3 blocks/CU.
// BM=BN=128: 8 waves (2x4, 64x32/wave), 96KB LDS, 1 block/CU.
// Every wave stages exactly 4 gloads/step (2 A + 2 B).
// ---------------------------------------------------------------------------
template <int MODE, int BM, int BN>
__global__ __launch_bounds__(BM == 128 ? 512 : 256, BM == 128 ? 2 : 3)
void gemm_kernel(
    const unsigned short* __restrict__ A, const unsigned short* __restrict__ Bt,
    const float* __restrict__ bias, int M, int N, int K,
    float* __restrict__ outf, const float* __restrict__ res,
    unsigned short* __restrict__ outb,
    unsigned short* __restrict__ kbuf, unsigned short* __restrict__ vtbuf) {
  constexpr int BK = 64;
  constexpr int NW  = (BM == 128) ? 8 : 4;
  constexpr int WNG = NW / 2;                   // waves along N
  constexpr int WR  = BM / 32;                  // 4 or 2 row-frags/wave
  constexpr int WC  = 2;                        // 2 col-frags/wave (32 cols)
  __shared__ unsigned short a_sh[3][BM * BK];
  __shared__ unsigned short b_sh[3][BN * BK];

  const int tid = threadIdx.x;
  const int wave = tid >> 6, lane = tid & 63;
  const int wm = wave / WNG, wn = wave % WNG;
  const int l15 = lane & 15, l4 = lane >> 4;

  const int nwg = gridDim.x, cpx = nwg >> 3;
  const int swz = (blockIdx.x & 7) * cpx + (blockIdx.x >> 3);
  const int GY = M / BM;
  const long bm0 = (long)(swz % GY) * BM;
  const long bn0 = (long)(swz / GY) * BN;

  const int sr8 = lane >> 3;
  const int gc  = ((lane & 7) ^ sr8) * 8;       // inverse-swizzled source chunk

  const unsigned short* agp[2];
  const unsigned short* bgp[2];
  int aoff[2], boff[2];
#pragma unroll
  for (int i = 0; i < 2; ++i) {
    const int r = (wave * 2 + i) * 8;           // covers BM (and BN) rows
    agp[i] = A + (bm0 + r + sr8) * (long)K + gc;
    aoff[i] = r * BK;
    bgp[i] = Bt + (bn0 + r + sr8) * (long)K + gc;
    boff[i] = r * BK;
  }

  auto stage = [&](int buf, int k0) {
#pragma unroll
    for (int i = 0; i < 2; ++i) gload16(agp[i] + k0, &a_sh[buf][aoff[i]]);
#pragma unroll
    for (int i = 0; i < 2; ++i) gload16(bgp[i] + k0, &b_sh[buf][boff[i]]);
  };

  f32x4 acc[WR][WC] = {};
  const int NT = K / BK;

  stage(0, 0);
  stage(1, BK);
  asm volatile("s_waitcnt vmcnt(4)" ::: "memory");   // tile 0 landed (tile 1 in flight)
  __syncthreads();

  for (int t = 0; t < NT; ++t) {
    const int cur = t % 3;
    const bool pf = (t + 2 < NT);
    if (pf) stage((t + 2) % 3, (t + 2) * BK);   // buf[(t+2)%3] consumed at t-1

#pragma unroll
    for (int kk = 0; kk < 2; ++kk) {
      bf16x8 af[WR], bfr[WC];
#pragma unroll
      for (int mf = 0; mf < WR; ++mf) {
        const int r = wm * (BM / 2) + mf * 16 + l15;
        const int c = ((kk * 4 + l4) ^ (r & 7)) * 8;
        af[mf] = *reinterpret_cast<const bf16x8*>(&a_sh[cur][r * BK + c]);
      }
#pragma unroll
      for (int nf = 0; nf < WC; ++nf) {
        const int r = wn * 32 + nf * 16 + l15;
        const int c = ((kk * 4 + l4) ^ (r & 7)) * 8;
        bfr[nf] = *reinterpret_cast<const bf16x8*>(&b_sh[cur][r * BK + c]);
      }
#pragma unroll
      for (int mf = 0; mf < WR; ++mf)
#pragma unroll
        for (int nf = 0; nf < WC; ++nf)
          acc[mf][nf] = __builtin_amdgcn_mfma_f32_16x16x32_bf16(af[mf], bfr[nf], acc[mf][nf], 0, 0, 0);
    }

    // own tile-(t+1) loads done (t+2's 4 stay in flight); barrier makes it collective
    if (pf) asm volatile("s_waitcnt vmcnt(4)" ::: "memory");
    else    asm volatile("s_waitcnt vmcnt(0)" ::: "memory");
    __syncthreads();
  }

#pragma unroll
  for (int mf = 0; mf < WR; ++mf) {
#pragma unroll
    for (int nf = 0; nf < WC; ++nf) {
#pragma unroll
      for (int r = 0; r < 4; ++r) {
        const long row = bm0 + wm * (BM / 2) + mf * 16 + 4 * l4 + r;
        const long col = bn0 + wn * 32 + nf * 16 + l15;
        float v = acc[mf][nf][r] + bias[col];
        if constexpr (MODE == 0) {
          const int n = (int)col;
          const int which = n >> 10, rem = n & 1023;
          const int head = rem >> 6, d = rem & 63;
          const int b = (int)(row >> 10), s = (int)(row & 1023);
          const unsigned short bv = f2bf(v);
          const long qi = ((long)(b * 16 + head) * 1024 + s) * 64 + d;
          if (which == 0)      outb[qi] = bv;
          else if (which == 1) kbuf[qi] = bv;
          else                 vtbuf[((long)(b * 16 + head) * 64 + d) * 1024 + s] = bv;
        } else if constexpr (MODE == 1) {
          outf[row * N + col] = v + res[row * N + col];
        } else if constexpr (MODE == 2) {
          float mv;
          if (v > 20.f) mv = v;
          else { const float t2 = __expf(v); const float u = t2 * t2 + 2.f * t2;
                 mv = v * u / (u + 2.f); }
          outb[row * (long)N + col] = f2bf(mv);
        } else {
          outf[row * N + col] = v + res[row * N + col];
        }
      }
    }
  }
}

// ---------------------------------------------------------------------------
// Flash attention (R6 structure): grid (S/128, B*H), 8 waves x 16 q-rows.
// Shuffle-free softmax; bias ping-pong register prefetch; dbuf gload_lds K/V.
// ---------------------------------------------------------------------------
__global__ __launch_bounds__(512, 2) void attn_kernel(
    const unsigned short* __restrict__ qb, const unsigned short* __restrict__ kb,
    const unsigned short* __restrict__ vtb, const float* __restrict__ bias,
    unsigned short* __restrict__ ctx) {
  constexpr int S = 1024;
  __shared__ unsigned short k_sh[2][64 * 64];
  __shared__ unsigned short vt_sh[2][64 * 64];
  __shared__ unsigned short p_sh[8][16 * 72];

  const int bh = blockIdx.y;
  const int q0 = blockIdx.x * 128;
  const int tid = threadIdx.x, wave = tid >> 6, lane = tid & 63;
  const int l15 = lane & 15, l4 = lane >> 4;

  const long qbase = ((long)bh * S + q0 + wave * 16 + l15) * 64;
  const bf16x8 qf0 = *reinterpret_cast<const bf16x8*>(qb + qbase + 8 * l4);
  const bf16x8 qf1 = *reinterpret_cast<const bf16x8*>(qb + qbase + 8 * l4 + 32);

  const int sr8 = lane >> 3;
  const int gchunk = ((lane & 7) ^ sr8) * 8;
  const long kbase = (long)bh * S * 64;
  const long vbase = (long)bh * 64 * S;

  const float* bB = bias + ((long)bh * S + q0 + wave * 16 + 4 * l4) * S + l15;

  f32x4 oacc[4] = {};
  float lacc[4] = {};
  float ba[4][4], bb2[4][4];

  auto stageKV = [&](int kv, int buf) {
    const int r = wave * 8;
    gload16(kb + kbase + (long)(kv + r + sr8) * 64 + gchunk, &k_sh[buf][r * 64]);
    gload16(vtb + vbase + (long)(r + sr8) * S + kv + gchunk, &vt_sh[buf][r * 64]);
  };

  stageKV(0, 0);
#pragma unroll
  for (int r = 0; r < 4; ++r)
#pragma unroll
    for (int nf = 0; nf < 4; ++nf)
      ba[r][nf] = bB[(long)r * S + nf * 16];
  asm volatile("s_waitcnt vmcnt(0)" ::: "memory");
  __syncthreads();

#pragma unroll 1
  for (int tt = 0; tt < 8; ++tt) {
    const int t0 = 2 * tt;
#pragma unroll
    for (int half = 0; half < 2; ++half) {
      const int t = t0 + half;
      const int cur = half, nxt = half ^ 1;
      float (*bcur)[4] = half ? bb2 : ba;
      float (*bnxt)[4] = half ? ba : bb2;

      if (t < 15) stageKV((t + 1) * 64, nxt);

      f32x4 sc[4];
#pragma unroll
      for (int nf = 0; nf < 4; ++nf) {
        const int r = nf * 16 + l15;
        const bf16x8 kf0 = *reinterpret_cast<const bf16x8*>(
            &k_sh[cur][r * 64 + ((l4) ^ (r & 7)) * 8]);
        const bf16x8 kf1 = *reinterpret_cast<const bf16x8*>(
            &k_sh[cur][r * 64 + ((l4 + 4) ^ (r & 7)) * 8]);
        f32x4 z = {};
        z = __builtin_amdgcn_mfma_f32_16x16x32_bf16(qf0, kf0, z, 0, 0, 0);
        sc[nf] = __builtin_amdgcn_mfma_f32_16x16x32_bf16(qf1, kf1, z, 0, 0, 0);
      }

      if (t < 15) {
        const float* bn = bB + (t + 1) * 64;
#pragma unroll
        for (int r = 0; r < 4; ++r)
#pragma unroll
          for (int nf = 0; nf < 4; ++nf)
            bnxt[r][nf] = bn[(long)r * S + nf * 16];
      }

      float pv[4][4];
#pragma unroll
      for (int r = 0; r < 4; ++r) {
        float ls = 0.f;
#pragma unroll
        for (int nf = 0; nf < 4; ++nf) {
          const float p = __expf(sc[nf][r] * 0.125f + bcur[r][nf]);
          pv[nf][r] = p;
          ls += p;
        }
        lacc[r] += ls;
      }

#pragma unroll
      for (int nf = 0; nf < 4; ++nf)
#pragma unroll
        for (int r = 0; r < 4; ++r)
          p_sh[wave][(4 * l4 + r) * 72 + nf * 16 + l15] = f2bf(pv[nf][r]);

      const bf16x8 pa0 = *reinterpret_cast<const bf16x8*>(&p_sh[wave][l15 * 72 + 8 * l4]);
      const bf16x8 pa1 = *reinterpret_cast<const bf16x8*>(&p_sh[wave][l15 * 72 + 8 * l4 + 32]);
#pragma unroll
      for (int nf = 0; nf < 4; ++nf) {
        const int r = nf * 16 + l15;
        const bf16x8 vf0 = *reinterpret_cast<const bf16x8*>(
            &vt_sh[cur][r * 64 + ((l4) ^ (r & 7)) * 8]);
        const bf16x8 vf1 = *reinterpret_cast<const bf16x8*>(
            &vt_sh[cur][r * 64 + ((l4 + 4) ^ (r & 7)) * 8]);
        oacc[nf] = __builtin_amdgcn_mfma_f32_16x16x32_bf16(pa0, vf0, oacc[nf], 0, 0, 0);
        oacc[nf] = __builtin_amdgcn_mfma_f32_16x16x32_bf16(pa1, vf1, oacc[nf], 0, 0, 0);
      }

      asm volatile("s_waitcnt vmcnt(0)" ::: "memory");
      __syncthreads();
    }
  }

#pragma unroll
  for (int r = 0; r < 4; ++r) {
    float v = lacc[r];
    v += __shfl_xor(v, 1);
    v += __shfl_xor(v, 2);
    v += __shfl_xor(v, 4);
    v += __shfl_xor(v, 8);
    lacc[r] = 1.f / v;
  }

  const int b = bh >> 4, h = bh & 15;
#pragma unroll
  for (int nf = 0; nf < 4; ++nf)
#pragma unroll
    for (int r = 0; r < 4; ++r) {
      const long s = q0 + wave * 16 + 4 * l4 + r;
      const long col = h * 64 + nf * 16 + l15;
      ctx[((long)b * S + s) * 1024 + col] = f2bf(oacc[nf][r] * lacc[r]);
    }
}

// ---------------------------------------------------------------------------
extern "C" void kernel_launch(void* const* d_in, const int* in_sizes, int n_in,
                              void* d_out, int out_size, void* d_ws, size_t ws_size,
                              hipStream_t stream) {
  const float* x    = (const float*)d_in[0];
  const float* ab   = (const float*)d_in[1];
  const float* ln1g = (const float*)d_in[2];
  const float* ln1b = (const float*)d_in[3];
  const float* Wqkv = (const float*)d_in[4];
  const float* bqkv = (const float*)d_in[5];
  const float* Wo   = (const float*)d_in[6];
  const float* bo   = (const float*)d_in[7];
  const float* ln2g = (const float*)d_in[8];
  const float* ln2b = (const float*)d_in[9];
  const float* W1   = (const float*)d_in[10];
  const float* b1   = (const float*)d_in[11];
  const float* W2   = (const float*)d_in[12];
  const float* b2   = (const float*)d_in[13];
  float* out = (float*)d_out;

  char* ws = (char*)d_ws;
  size_t off = 0;
  auto alloc = [&](size_t bytes) {
    char* p = ws + off;
    off += (bytes + 255) & ~(size_t)255;
    return p;
  };
  unsigned short* wqkv_t = (unsigned short*)alloc((size_t)3072 * 1024 * 2);
  unsigned short* wo_t   = (unsigned short*)alloc((size_t)1024 * 1024 * 2);
  unsigned short* w1_t   = (unsigned short*)alloc((size_t)4096 * 1024 * 2);
  unsigned short* w2_t   = (unsigned short*)alloc((size_t)4096 * 1024 * 2);
  unsigned short* h1     = (unsigned short*)alloc((size_t)2048 * 1024 * 2);  // ffn1 aliases h1..vtbuf
  unsigned short* qbuf   = (unsigned short*)alloc((size_t)2048 * 1024 * 2);
  unsigned short* kbuf   = (unsigned short*)alloc((size_t)2048 * 1024 * 2);
  unsigned short* vtbuf  = (unsigned short*)alloc((size_t)2048 * 1024 * 2);
  unsigned short* ctx    = (unsigned short*)alloc((size_t)2048 * 1024 * 2);
  unsigned short* h2     = (unsigned short*)alloc((size_t)2048 * 1024 * 2);
  float*          r1     = (float*)alloc((size_t)2048 * 1024 * 4);
  unsigned short* ffn1   = h1;  // 16MB alias over h1/qbuf/kbuf/vtbuf (dead after attn)
  (void)ws_size; (void)in_sizes; (void)n_in; (void)out_size;

  convert_ln<<<14336, dim3(32, 8), 0, stream>>>(Wqkv, Wo, W1, W2, x, ln1g, ln1b,
                                                wqkv_t, wo_t, w1_t, w2_t, h1);

  gemm_kernel<0, 64, 64><<<1536, 256, 0, stream>>>(h1, wqkv_t, bqkv, 2048, 3072, 1024,
                                                   nullptr, nullptr, qbuf, kbuf, vtbuf);

  attn_kernel<<<dim3(8, 32), 512, 0, stream>>>(qbuf, kbuf, vtbuf, ab, ctx);

  gemm_kernel<1, 64, 64><<<512, 256, 0, stream>>>(ctx, wo_t, bo, 2048, 1024, 1024,
                                                  r1, x, nullptr, nullptr, nullptr);

  ln_kernel<<<2048, 256, 0, stream>>>(r1, ln2g, ln2b, h2);

  gemm_kernel<2, 128, 128><<<512, 512, 0, stream>>>(h2, w1_t, b1, 2048, 4096, 1024,
                                                    nullptr, nullptr, ffn1, nullptr, nullptr);

  gemm_kernel<3, 64, 64><<<512, 256, 0, stream>>>(ffn1, w2_t, b2, 2048, 1024, 4096,
                                                  out, r1, nullptr, nullptr, nullptr);
}

// Round 8
// 173.557 us; speedup vs baseline: 1.1118x; 1.1118x over previous
//
#include <hip/hip_runtime.h>

// ---------------------------------------------------------------------------
// TransformerBlock: LN1 -> QKV -> attn(+bias, softmax) -> Wo(+x) -> LN2
//                   -> FFN1(+mish) -> FFN2(+residual)
// fp32 I/O, bf16 MFMA GEMMs (16x16x32), flash-style attention.
// R8: revert to R6's proven 2-stage GEMM (vmcnt(0), dbuf, 2-3 blocks/CU);
//     keep convert+LN1 fusion from R7. R7's 3-stage vmcnt(4) pipeline and
//     64x64 QKV / 8-wave FFN1 geometry regressed (178->193) — occupancy and
//     A-panel traffic beat pipeline depth at these tile sizes.
// ---------------------------------------------------------------------------

typedef __attribute__((ext_vector_type(8))) __bf16 bf16x8;
typedef __attribute__((ext_vector_type(4))) float  f32x4;

__device__ __forceinline__ unsigned short f2bf(float f) {
  unsigned int u = __builtin_bit_cast(unsigned int, f);
  u += 0x7fffu + ((u >> 16) & 1u);          // round-to-nearest-even
  return (unsigned short)(u >> 16);
}

__device__ __forceinline__ void gload16(const void* g, void* l) {
  __builtin_amdgcn_global_load_lds(
      (const __attribute__((address_space(1))) void*)g,
      (__attribute__((address_space(3))) void*)l, 16, 0, 0);
}

// ---------------------------------------------------------------------------
// Fused: 4 weight converts fp32(KxN)->bf16 transposed(NxK)  +  LN1.
// blocks 0..12287: converts; 12288..14335: LN1 rows.
// ---------------------------------------------------------------------------
__global__ __launch_bounds__(256) void convert_ln(
    const float* __restrict__ Wqkv, const float* __restrict__ Wo,
    const float* __restrict__ W1, const float* __restrict__ W2,
    const float* __restrict__ x, const float* __restrict__ g,
    const float* __restrict__ bln,
    unsigned short* __restrict__ wqkv_t, unsigned short* __restrict__ wo_t,
    unsigned short* __restrict__ w1_t, unsigned short* __restrict__ w2_t,
    unsigned short* __restrict__ h1) {
  __shared__ float tile[32][33];
  __shared__ float ps[4], ps2[4];
  const int id = blockIdx.x;
  const int tx = threadIdx.x, ty = threadIdx.y;   // (32,8)

  if (id < 12288) {
    const float* W; unsigned short* Wt; int K, N, t;
    if (id < 3072)      { W = Wqkv; Wt = wqkv_t; K = 1024; N = 3072; t = id; }
    else if (id < 4096) { W = Wo;   Wt = wo_t;   K = 1024; N = 1024; t = id - 3072; }
    else if (id < 8192) { W = W1;   Wt = w1_t;   K = 1024; N = 4096; t = id - 4096; }
    else                { W = W2;   Wt = w2_t;   K = 4096; N = 1024; t = id - 8192; }
    const int nx = N >> 5;
    const int n0 = (t % nx) * 32, k0 = (t / nx) * 32;
#pragma unroll
    for (int r = 0; r < 4; ++r)
      tile[ty + 8 * r][tx] = W[(size_t)(k0 + ty + 8 * r) * N + n0 + tx];
    __syncthreads();
#pragma unroll
    for (int r = 0; r < 4; ++r)
      Wt[(size_t)(n0 + ty + 8 * r) * K + k0 + tx] = f2bf(tile[tx][ty + 8 * r]);
  } else {
    const int row = id - 12288;
    const int t = ty * 32 + tx;
    const float4 v = reinterpret_cast<const float4*>(x + (size_t)row * 1024)[t];
    float s  = v.x + v.y + v.z + v.w;
    float s2 = v.x * v.x + v.y * v.y + v.z * v.z + v.w * v.w;
#pragma unroll
    for (int m = 1; m < 64; m <<= 1) { s += __shfl_xor(s, m); s2 += __shfl_xor(s2, m); }
    const int wv = t >> 6;
    if ((t & 63) == 0) { ps[wv] = s; ps2[wv] = s2; }
    __syncthreads();
    float ts = 0.f, ts2 = 0.f;
#pragma unroll
    for (int i = 0; i < 4; ++i) { ts += ps[i]; ts2 += ps2[i]; }
    const float mu = ts * (1.f / 1024.f);
    const float var = ts2 * (1.f / 1024.f) - mu * mu;
    const float rstd = rsqrtf(var + 1e-5f);
    const float4 gg = reinterpret_cast<const float4*>(g)[t];
    const float4 bb = reinterpret_cast<const float4*>(bln)[t];
    ushort4 ov;
    ov.x = f2bf((v.x - mu) * rstd * gg.x + bb.x);
    ov.y = f2bf((v.y - mu) * rstd * gg.y + bb.y);
    ov.z = f2bf((v.z - mu) * rstd * gg.z + bb.z);
    ov.w = f2bf((v.w - mu) * rstd * gg.w + bb.w);
    *reinterpret_cast<ushort4*>(h1 + (size_t)row * 1024 + t * 4) = ov;
  }
}

// ---------------------------------------------------------------------------
// LayerNorm (standalone, for LN2).
// ---------------------------------------------------------------------------
__global__ __launch_bounds__(256) void ln_kernel(const float* __restrict__ in,
                                                 const float* __restrict__ g,
                                                 const float* __restrict__ b,
                                                 unsigned short* __restrict__ out) {
  const int row = blockIdx.x;
  const int t = threadIdx.x;
  const float4 v = reinterpret_cast<const float4*>(in + (size_t)row * 1024)[t];
  float s  = v.x + v.y + v.z + v.w;
  float s2 = v.x * v.x + v.y * v.y + v.z * v.z + v.w * v.w;
#pragma unroll
  for (int m = 1; m < 64; m <<= 1) { s += __shfl_xor(s, m); s2 += __shfl_xor(s2, m); }
  __shared__ float ps[4], ps2[4];
  const int wv = t >> 6;
  if ((t & 63) == 0) { ps[wv] = s; ps2[wv] = s2; }
  __syncthreads();
  float ts = 0.f, ts2 = 0.f;
#pragma unroll
  for (int i = 0; i < 4; ++i) { ts += ps[i]; ts2 += ps2[i]; }
  const float mu = ts * (1.f / 1024.f);
  const float var = ts2 * (1.f / 1024.f) - mu * mu;
  const float rstd = rsqrtf(var + 1e-5f);
  const float4 gg = reinterpret_cast<const float4*>(g)[t];
  const float4 bb = reinterpret_cast<const float4*>(b)[t];
  ushort4 ov;
  ov.x = f2bf((v.x - mu) * rstd * gg.x + bb.x);
  ov.y = f2bf((v.y - mu) * rstd * gg.y + bb.y);
  ov.z = f2bf((v.z - mu) * rstd * gg.z + bb.z);
  ov.w = f2bf((v.w - mu) * rstd * gg.w + bb.w);
  *reinterpret_cast<ushort4*>(out + (size_t)row * 1024 + t * 4) = ov;
}

// ---------------------------------------------------------------------------
// GEMM (R6-proven): C(MxN) = A(MxK bf16 rm) @ Bt(NxK bf16 rm)^T + bias
// BM in {64,128}, BN in {64,128}, BK=64. 2-stage prefetch: stage tile t+1
// into the other LDS buffer before computing tile t; one vmcnt(0)+barrier
// per K-step. XOR chunk swizzle both-sides; XCD-chunked x-major order.
// ---------------------------------------------------------------------------
template <int MODE, int BM, int BN>
__global__ __launch_bounds__(256, 2) void gemm_kernel(
    const unsigned short* __restrict__ A, const unsigned short* __restrict__ Bt,
    const float* __restrict__ bias, int M, int N, int K,
    float* __restrict__ outf, const float* __restrict__ res,
    unsigned short* __restrict__ outb,
    unsigned short* __restrict__ kbuf, unsigned short* __restrict__ vtbuf) {
  constexpr int BK = 64;
  constexpr int WN = (BN >= 128 || BM == 64) ? 2 : 1;
  constexpr int WM = 4 / WN;
  constexpr int WR = BM / WM / 16;
  constexpr int WC = BN / WN / 16;
  constexpr int AI = BM / 32, BI = BN / 32;     // staging instrs per matrix
  __shared__ unsigned short a_sh[2][BM * BK];
  __shared__ unsigned short b_sh[2][BN * BK];

  const int tid = threadIdx.x;
  const int wave = tid >> 6, lane = tid & 63;
  const int wm = wave / WN, wn = wave % WN;
  const int l15 = lane & 15, l4 = lane >> 4;

  const int nwg = gridDim.x, cpx = nwg >> 3;
  const int swz = (blockIdx.x & 7) * cpx + (blockIdx.x >> 3);
  const int GY = M / BM;
  const long bm0 = (long)(swz % GY) * BM;
  const long bn0 = (long)(swz / GY) * BN;

  const int sr8 = lane >> 3;
  const int gc  = ((lane & 7) ^ sr8) * 8;       // inverse-swizzled source chunk

  const unsigned short* agp[AI];
  const unsigned short* bgp[BI];
  int aoff[AI], boff[BI];
#pragma unroll
  for (int i = 0; i < AI; ++i) {
    const int r = wave * (BM / 4) + i * 8;
    agp[i] = A + (bm0 + r + sr8) * (long)K + gc;
    aoff[i] = r * BK;
  }
#pragma unroll
  for (int i = 0; i < BI; ++i) {
    const int r = wave * (BN / 4) + i * 8;
    bgp[i] = Bt + (bn0 + r + sr8) * (long)K + gc;
    boff[i] = r * BK;
  }

  auto stage = [&](int buf, int k0) {
#pragma unroll
    for (int i = 0; i < AI; ++i) gload16(agp[i] + k0, &a_sh[buf][aoff[i]]);
#pragma unroll
    for (int i = 0; i < BI; ++i) gload16(bgp[i] + k0, &b_sh[buf][boff[i]]);
  };

  f32x4 acc[WR][WC] = {};

  stage(0, 0);
  asm volatile("s_waitcnt vmcnt(0)" ::: "memory");
  __syncthreads();

  const int NT = K / BK;
  for (int t = 0; t < NT; ++t) {
    const int cur = t & 1;
    if (t + 1 < NT) stage(cur ^ 1, (t + 1) * BK);   // prefetch next tile

#pragma unroll
    for (int kk = 0; kk < 2; ++kk) {
      bf16x8 af[WR], bfr[WC];
#pragma unroll
      for (int mf = 0; mf < WR; ++mf) {
        const int r = wm * (BM / WM) + mf * 16 + l15;
        const int c = ((kk * 4 + l4) ^ (r & 7)) * 8;
        af[mf] = *reinterpret_cast<const bf16x8*>(&a_sh[cur][r * BK + c]);
      }
#pragma unroll
      for (int nf = 0; nf < WC; ++nf) {
        const int r = wn * (BN / WN) + nf * 16 + l15;
        const int c = ((kk * 4 + l4) ^ (r & 7)) * 8;
        bfr[nf] = *reinterpret_cast<const bf16x8*>(&b_sh[cur][r * BK + c]);
      }
#pragma unroll
      for (int mf = 0; mf < WR; ++mf)
#pragma unroll
        for (int nf = 0; nf < WC; ++nf)
          acc[mf][nf] = __builtin_amdgcn_mfma_f32_16x16x32_bf16(af[mf], bfr[nf], acc[mf][nf], 0, 0, 0);
    }

    asm volatile("s_waitcnt vmcnt(0)" ::: "memory");  // prefetch landed
    __syncthreads();                                  // buf[cur] consumed by all
  }

#pragma unroll
  for (int mf = 0; mf < WR; ++mf) {
#pragma unroll
    for (int nf = 0; nf < WC; ++nf) {
#pragma unroll
      for (int r = 0; r < 4; ++r) {
        const long row = bm0 + wm * (BM / WM) + mf * 16 + 4 * l4 + r;
        const long col = bn0 + wn * (BN / WN) + nf * 16 + l15;
        float v = acc[mf][nf][r] + bias[col];
        if constexpr (MODE == 0) {
          const int n = (int)col;
          const int which = n >> 10, rem = n & 1023;
          const int head = rem >> 6, d = rem & 63;
          const int b = (int)(row >> 10), s = (int)(row & 1023);
          const unsigned short bv = f2bf(v);
          const long qi = ((long)(b * 16 + head) * 1024 + s) * 64 + d;
          if (which == 0)      outb[qi] = bv;
          else if (which == 1) kbuf[qi] = bv;
          else                 vtbuf[((long)(b * 16 + head) * 64 + d) * 1024 + s] = bv;
        } else if constexpr (MODE == 1) {
          outf[row * N + col] = v + res[row * N + col];
        } else if constexpr (MODE == 2) {
          float mv;
          if (v > 20.f) mv = v;
          else { const float t2 = __expf(v); const float u = t2 * t2 + 2.f * t2;
                 mv = v * u / (u + 2.f); }
          outb[row * (long)N + col] = f2bf(mv);
        } else {
          outf[row * N + col] = v + res[row * N + col];
        }
      }
    }
  }
}

// ---------------------------------------------------------------------------
// Flash attention (R6 structure): grid (S/128, B*H), 8 waves x 16 q-rows.
// Shuffle-free softmax; bias ping-pong register prefetch; dbuf gload_lds K/V.
// ---------------------------------------------------------------------------
__global__ __launch_bounds__(512, 2) void attn_kernel(
    const unsigned short* __restrict__ qb, const unsigned short* __restrict__ kb,
    const unsigned short* __restrict__ vtb, const float* __restrict__ bias,
    unsigned short* __restrict__ ctx) {
  constexpr int S = 1024;
  __shared__ unsigned short k_sh[2][64 * 64];
  __shared__ unsigned short vt_sh[2][64 * 64];
  __shared__ unsigned short p_sh[8][16 * 72];

  const int bh = blockIdx.y;
  const int q0 = blockIdx.x * 128;
  const int tid = threadIdx.x, wave = tid >> 6, lane = tid & 63;
  const int l15 = lane & 15, l4 = lane >> 4;

  const long qbase = ((long)bh * S + q0 + wave * 16 + l15) * 64;
  const bf16x8 qf0 = *reinterpret_cast<const bf16x8*>(qb + qbase + 8 * l4);
  const bf16x8 qf1 = *reinterpret_cast<const bf16x8*>(qb + qbase + 8 * l4 + 32);

  const int sr8 = lane >> 3;
  const int gchunk = ((lane & 7) ^ sr8) * 8;
  const long kbase = (long)bh * S * 64;
  const long vbase = (long)bh * 64 * S;

  const float* bB = bias + ((long)bh * S + q0 + wave * 16 + 4 * l4) * S + l15;

  f32x4 oacc[4] = {};
  float lacc[4] = {};
  float ba[4][4], bb2[4][4];

  auto stageKV = [&](int kv, int buf) {
    const int r = wave * 8;
    gload16(kb + kbase + (long)(kv + r + sr8) * 64 + gchunk, &k_sh[buf][r * 64]);
    gload16(vtb + vbase + (long)(r + sr8) * S + kv + gchunk, &vt_sh[buf][r * 64]);
  };

  stageKV(0, 0);
#pragma unroll
  for (int r = 0; r < 4; ++r)
#pragma unroll
    for (int nf = 0; nf < 4; ++nf)
      ba[r][nf] = bB[(long)r * S + nf * 16];
  asm volatile("s_waitcnt vmcnt(0)" ::: "memory");
  __syncthreads();

#pragma unroll 1
  for (int tt = 0; tt < 8; ++tt) {
    const int t0 = 2 * tt;
#pragma unroll
    for (int half = 0; half < 2; ++half) {
      const int t = t0 + half;
      const int cur = half, nxt = half ^ 1;
      float (*bcur)[4] = half ? bb2 : ba;
      float (*bnxt)[4] = half ? ba : bb2;

      if (t < 15) stageKV((t + 1) * 64, nxt);

      f32x4 sc[4];
#pragma unroll
      for (int nf = 0; nf < 4; ++nf) {
        const int r = nf * 16 + l15;
        const bf16x8 kf0 = *reinterpret_cast<const bf16x8*>(
            &k_sh[cur][r * 64 + ((l4) ^ (r & 7)) * 8]);
        const bf16x8 kf1 = *reinterpret_cast<const bf16x8*>(
            &k_sh[cur][r * 64 + ((l4 + 4) ^ (r & 7)) * 8]);
        f32x4 z = {};
        z = __builtin_amdgcn_mfma_f32_16x16x32_bf16(qf0, kf0, z, 0, 0, 0);
        sc[nf] = __builtin_amdgcn_mfma_f32_16x16x32_bf16(qf1, kf1, z, 0, 0, 0);
      }

      if (t < 15) {
        const float* bn = bB + (t + 1) * 64;
#pragma unroll
        for (int r = 0; r < 4; ++r)
#pragma unroll
          for (int nf = 0; nf < 4; ++nf)
            bnxt[r][nf] = bn[(long)r * S + nf * 16];
      }

      float pv[4][4];
#pragma unroll
      for (int r = 0; r < 4; ++r) {
        float ls = 0.f;
#pragma unroll
        for (int nf = 0; nf < 4; ++nf) {
          const float p = __expf(sc[nf][r] * 0.125f + bcur[r][nf]);
          pv[nf][r] = p;
          ls += p;
        }
        lacc[r] += ls;
      }

#pragma unroll
      for (int nf = 0; nf < 4; ++nf)
#pragma unroll
        for (int r = 0; r < 4; ++r)
          p_sh[wave][(4 * l4 + r) * 72 + nf * 16 + l15] = f2bf(pv[nf][r]);

      const bf16x8 pa0 = *reinterpret_cast<const bf16x8*>(&p_sh[wave][l15 * 72 + 8 * l4]);
      const bf16x8 pa1 = *reinterpret_cast<const bf16x8*>(&p_sh[wave][l15 * 72 + 8 * l4 + 32]);
#pragma unroll
      for (int nf = 0; nf < 4; ++nf) {
        const int r = nf * 16 + l15;
        const bf16x8 vf0 = *reinterpret_cast<const bf16x8*>(
            &vt_sh[cur][r * 64 + ((l4) ^ (r & 7)) * 8]);
        const bf16x8 vf1 = *reinterpret_cast<const bf16x8*>(
            &vt_sh[cur][r * 64 + ((l4 + 4) ^ (r & 7)) * 8]);
        oacc[nf] = __builtin_amdgcn_mfma_f32_16x16x32_bf16(pa0, vf0, oacc[nf], 0, 0, 0);
        oacc[nf] = __builtin_amdgcn_mfma_f32_16x16x32_bf16(pa1, vf1, oacc[nf], 0, 0, 0);
      }

      asm volatile("s_waitcnt vmcnt(0)" ::: "memory");
      __syncthreads();
    }
  }

#pragma unroll
  for (int r = 0; r < 4; ++r) {
    float v = lacc[r];
    v += __shfl_xor(v, 1);
    v += __shfl_xor(v, 2);
    v += __shfl_xor(v, 4);
    v += __shfl_xor(v, 8);
    lacc[r] = 1.f / v;
  }

  const int b = bh >> 4, h = bh & 15;
#pragma unroll
  for (int nf = 0; nf < 4; ++nf)
#pragma unroll
    for (int r = 0; r < 4; ++r) {
      const long s = q0 + wave * 16 + 4 * l4 + r;
      const long col = h * 64 + nf * 16 + l15;
      ctx[((long)b * S + s) * 1024 + col] = f2bf(oacc[nf][r] * lacc[r]);
    }
}

// ---------------------------------------------------------------------------
extern "C" void kernel_launch(void* const* d_in, const int* in_sizes, int n_in,
                              void* d_out, int out_size, void* d_ws, size_t ws_size,
                              hipStream_t stream) {
  const float* x    = (const float*)d_in[0];
  const float* ab   = (const float*)d_in[1];
  const float* ln1g = (const float*)d_in[2];
  const float* ln1b = (const float*)d_in[3];
  const float* Wqkv = (const float*)d_in[4];
  const float* bqkv = (const float*)d_in[5];
  const float* Wo   = (const float*)d_in[6];
  const float* bo   = (const float*)d_in[7];
  const float* ln2g = (const float*)d_in[8];
  const float* ln2b = (const float*)d_in[9];
  const float* W1   = (const float*)d_in[10];
  const float* b1   = (const float*)d_in[11];
  const float* W2   = (const float*)d_in[12];
  const float* b2   = (const float*)d_in[13];
  float* out = (float*)d_out;

  char* ws = (char*)d_ws;
  size_t off = 0;
  auto alloc = [&](size_t bytes) {
    char* p = ws + off;
    off += (bytes + 255) & ~(size_t)255;
    return p;
  };
  unsigned short* wqkv_t = (unsigned short*)alloc((size_t)3072 * 1024 * 2);
  unsigned short* wo_t   = (unsigned short*)alloc((size_t)1024 * 1024 * 2);
  unsigned short* w1_t   = (unsigned short*)alloc((size_t)4096 * 1024 * 2);
  unsigned short* w2_t   = (unsigned short*)alloc((size_t)4096 * 1024 * 2);
  unsigned short* h1     = (unsigned short*)alloc((size_t)2048 * 1024 * 2);  // ffn1 aliases h1..vtbuf
  unsigned short* qbuf   = (unsigned short*)alloc((size_t)2048 * 1024 * 2);
  unsigned short* kbuf   = (unsigned short*)alloc((size_t)2048 * 1024 * 2);
  unsigned short* vtbuf  = (unsigned short*)alloc((size_t)2048 * 1024 * 2);
  unsigned short* ctx    = (unsigned short*)alloc((size_t)2048 * 1024 * 2);
  unsigned short* h2     = (unsigned short*)alloc((size_t)2048 * 1024 * 2);
  float*          r1     = (float*)alloc((size_t)2048 * 1024 * 4);
  unsigned short* ffn1   = h1;  // 16MB alias over h1/qbuf/kbuf/vtbuf (dead after attn)
  (void)ws_size; (void)in_sizes; (void)n_in; (void)out_size;

  convert_ln<<<14336, dim3(32, 8), 0, stream>>>(Wqkv, Wo, W1, W2, x, ln1g, ln1b,
                                                wqkv_t, wo_t, w1_t, w2_t, h1);

  gemm_kernel<0, 128, 128><<<384, 256, 0, stream>>>(h1, wqkv_t, bqkv, 2048, 3072, 1024,
                                                    nullptr, nullptr, qbuf, kbuf, vtbuf);

  attn_kernel<<<dim3(8, 32), 512, 0, stream>>>(qbuf, kbuf, vtbuf, ab, ctx);

  gemm_kernel<1, 64, 64><<<512, 256, 0, stream>>>(ctx, wo_t, bo, 2048, 1024, 1024,
                                                  r1, x, nullptr, nullptr, nullptr);

  ln_kernel<<<2048, 256, 0, stream>>>(r1, ln2g, ln2b, h2);

  gemm_kernel<2, 128, 128><<<512, 256, 0, stream>>>(h2, w1_t, b1, 2048, 4096, 1024,
                                                    nullptr, nullptr, ffn1, nullptr, nullptr);

  gemm_kernel<3, 64, 64><<<512, 256, 0, stream>>>(ffn1, w2_t, b2, 2048, 1024, 4096,
                                                  out, r1, nullptr, nullptr, nullptr);
}

// Round 9
// 168.155 us; speedup vs baseline: 1.1475x; 1.0321x over previous
//
#include <hip/hip_runtime.h>

// ---------------------------------------------------------------------------
// TransformerBlock: LN1 -> QKV -> attn(+bias, softmax) -> Wo(+x) -> LN2
//                   -> FFN1(+mish) -> FFN2(+residual)
// fp32 I/O, bf16 MFMA GEMMs (16x16x32), flash-style attention.
// R9: 2-D blocked block-traversal within XCD chunks (8 A-panels x cpx/8
//     B-panels per chunk) to cut A-panel HBM re-fetch. Rest = R8.
// ---------------------------------------------------------------------------

typedef __attribute__((ext_vector_type(8))) __bf16 bf16x8;
typedef __attribute__((ext_vector_type(4))) float  f32x4;

__device__ __forceinline__ unsigned short f2bf(float f) {
  unsigned int u = __builtin_bit_cast(unsigned int, f);
  u += 0x7fffu + ((u >> 16) & 1u);          // round-to-nearest-even
  return (unsigned short)(u >> 16);
}

__device__ __forceinline__ void gload16(const void* g, void* l) {
  __builtin_amdgcn_global_load_lds(
      (const __attribute__((address_space(1))) void*)g,
      (__attribute__((address_space(3))) void*)l, 16, 0, 0);
}

// ---------------------------------------------------------------------------
// Fused: 4 weight converts fp32(KxN)->bf16 transposed(NxK)  +  LN1.
// blocks 0..12287: converts; 12288..14335: LN1 rows.
// ---------------------------------------------------------------------------
__global__ __launch_bounds__(256) void convert_ln(
    const float* __restrict__ Wqkv, const float* __restrict__ Wo,
    const float* __restrict__ W1, const float* __restrict__ W2,
    const float* __restrict__ x, const float* __restrict__ g,
    const float* __restrict__ bln,
    unsigned short* __restrict__ wqkv_t, unsigned short* __restrict__ wo_t,
    unsigned short* __restrict__ w1_t, unsigned short* __restrict__ w2_t,
    unsigned short* __restrict__ h1) {
  __shared__ float tile[32][33];
  __shared__ float ps[4], ps2[4];
  const int id = blockIdx.x;
  const int tx = threadIdx.x, ty = threadIdx.y;   // (32,8)

  if (id < 12288) {
    const float* W; unsigned short* Wt; int K, N, t;
    if (id < 3072)      { W = Wqkv; Wt = wqkv_t; K = 1024; N = 3072; t = id; }
    else if (id < 4096) { W = Wo;   Wt = wo_t;   K = 1024; N = 1024; t = id - 3072; }
    else if (id < 8192) { W = W1;   Wt = w1_t;   K = 1024; N = 4096; t = id - 4096; }
    else                { W = W2;   Wt = w2_t;   K = 4096; N = 1024; t = id - 8192; }
    const int nx = N >> 5;
    const int n0 = (t % nx) * 32, k0 = (t / nx) * 32;
#pragma unroll
    for (int r = 0; r < 4; ++r)
      tile[ty + 8 * r][tx] = W[(size_t)(k0 + ty + 8 * r) * N + n0 + tx];
    __syncthreads();
#pragma unroll
    for (int r = 0; r < 4; ++r)
      Wt[(size_t)(n0 + ty + 8 * r) * K + k0 + tx] = f2bf(tile[tx][ty + 8 * r]);
  } else {
    const int row = id - 12288;
    const int t = ty * 32 + tx;
    const float4 v = reinterpret_cast<const float4*>(x + (size_t)row * 1024)[t];
    float s  = v.x + v.y + v.z + v.w;
    float s2 = v.x * v.x + v.y * v.y + v.z * v.z + v.w * v.w;
#pragma unroll
    for (int m = 1; m < 64; m <<= 1) { s += __shfl_xor(s, m); s2 += __shfl_xor(s2, m); }
    const int wv = t >> 6;
    if ((t & 63) == 0) { ps[wv] = s; ps2[wv] = s2; }
    __syncthreads();
    float ts = 0.f, ts2 = 0.f;
#pragma unroll
    for (int i = 0; i < 4; ++i) { ts += ps[i]; ts2 += ps2[i]; }
    const float mu = ts * (1.f / 1024.f);
    const float var = ts2 * (1.f / 1024.f) - mu * mu;
    const float rstd = rsqrtf(var + 1e-5f);
    const float4 gg = reinterpret_cast<const float4*>(g)[t];
    const float4 bb = reinterpret_cast<const float4*>(bln)[t];
    ushort4 ov;
    ov.x = f2bf((v.x - mu) * rstd * gg.x + bb.x);
    ov.y = f2bf((v.y - mu) * rstd * gg.y + bb.y);
    ov.z = f2bf((v.z - mu) * rstd * gg.z + bb.z);
    ov.w = f2bf((v.w - mu) * rstd * gg.w + bb.w);
    *reinterpret_cast<ushort4*>(h1 + (size_t)row * 1024 + t * 4) = ov;
  }
}

// ---------------------------------------------------------------------------
// LayerNorm (standalone, for LN2).
// ---------------------------------------------------------------------------
__global__ __launch_bounds__(256) void ln_kernel(const float* __restrict__ in,
                                                 const float* __restrict__ g,
                                                 const float* __restrict__ b,
                                                 unsigned short* __restrict__ out) {
  const int row = blockIdx.x;
  const int t = threadIdx.x;
  const float4 v = reinterpret_cast<const float4*>(in + (size_t)row * 1024)[t];
  float s  = v.x + v.y + v.z + v.w;
  float s2 = v.x * v.x + v.y * v.y + v.z * v.z + v.w * v.w;
#pragma unroll
  for (int m = 1; m < 64; m <<= 1) { s += __shfl_xor(s, m); s2 += __shfl_xor(s2, m); }
  __shared__ float ps[4], ps2[4];
  const int wv = t >> 6;
  if ((t & 63) == 0) { ps[wv] = s; ps2[wv] = s2; }
  __syncthreads();
  float ts = 0.f, ts2 = 0.f;
#pragma unroll
  for (int i = 0; i < 4; ++i) { ts += ps[i]; ts2 += ps2[i]; }
  const float mu = ts * (1.f / 1024.f);
  const float var = ts2 * (1.f / 1024.f) - mu * mu;
  const float rstd = rsqrtf(var + 1e-5f);
  const float4 gg = reinterpret_cast<const float4*>(g)[t];
  const float4 bb = reinterpret_cast<const float4*>(b)[t];
  ushort4 ov;
  ov.x = f2bf((v.x - mu) * rstd * gg.x + bb.x);
  ov.y = f2bf((v.y - mu) * rstd * gg.y + bb.y);
  ov.z = f2bf((v.z - mu) * rstd * gg.z + bb.z);
  ov.w = f2bf((v.w - mu) * rstd * gg.w + bb.w);
  *reinterpret_cast<ushort4*>(out + (size_t)row * 1024 + t * 4) = ov;
}

// ---------------------------------------------------------------------------
// GEMM (R6-proven loop): C(MxN) = A(MxK bf16 rm) @ Bt(NxK bf16 rm)^T + bias
// 2-stage prefetch, one vmcnt(0)+barrier per K-step, XOR chunk swizzle.
// R9 block order: XCD-chunked, then 2-D blocked inside the chunk —
// swz = sr*(8*GX) + sc*8 + r  ->  tile(sr*8+r, sc).  Each XCD chunk touches
// 8 A-panels and cpx/8 B-panels (requires GY%8==0; holds for all 4 GEMMs).
// ---------------------------------------------------------------------------
template <int MODE, int BM, int BN>
__global__ __launch_bounds__(256, 2) void gemm_kernel(
    const unsigned short* __restrict__ A, const unsigned short* __restrict__ Bt,
    const float* __restrict__ bias, int M, int N, int K,
    float* __restrict__ outf, const float* __restrict__ res,
    unsigned short* __restrict__ outb,
    unsigned short* __restrict__ kbuf, unsigned short* __restrict__ vtbuf) {
  constexpr int BK = 64;
  constexpr int WN = (BN >= 128 || BM == 64) ? 2 : 1;
  constexpr int WM = 4 / WN;
  constexpr int WR = BM / WM / 16;
  constexpr int WC = BN / WN / 16;
  constexpr int AI = BM / 32, BI = BN / 32;
  __shared__ unsigned short a_sh[2][BM * BK];
  __shared__ unsigned short b_sh[2][BN * BK];

  const int tid = threadIdx.x;
  const int wave = tid >> 6, lane = tid & 63;
  const int wm = wave / WN, wn = wave % WN;
  const int l15 = lane & 15, l4 = lane >> 4;

  const int nwg = gridDim.x, cpx = nwg >> 3;
  const int swz = (blockIdx.x & 7) * cpx + (blockIdx.x >> 3);
  const int GX = N / BN;
  const int sr  = swz / (8 * GX);
  const int rem = swz % (8 * GX);
  const long bm0 = (long)(sr * 8 + (rem & 7)) * BM;
  const long bn0 = (long)(rem >> 3) * BN;

  const int sr8 = lane >> 3;
  const int gc  = ((lane & 7) ^ sr8) * 8;       // inverse-swizzled source chunk

  const unsigned short* agp[AI];
  const unsigned short* bgp[BI];
  int aoff[AI], boff[BI];
#pragma unroll
  for (int i = 0; i < AI; ++i) {
    const int r = wave * (BM / 4) + i * 8;
    agp[i] = A + (bm0 + r + sr8) * (long)K + gc;
    aoff[i] = r * BK;
  }
#pragma unroll
  for (int i = 0; i < BI; ++i) {
    const int r = wave * (BN / 4) + i * 8;
    bgp[i] = Bt + (bn0 + r + sr8) * (long)K + gc;
    boff[i] = r * BK;
  }

  auto stage = [&](int buf, int k0) {
#pragma unroll
    for (int i = 0; i < AI; ++i) gload16(agp[i] + k0, &a_sh[buf][aoff[i]]);
#pragma unroll
    for (int i = 0; i < BI; ++i) gload16(bgp[i] + k0, &b_sh[buf][boff[i]]);
  };

  f32x4 acc[WR][WC] = {};

  stage(0, 0);
  asm volatile("s_waitcnt vmcnt(0)" ::: "memory");
  __syncthreads();

  const int NT = K / BK;
  for (int t = 0; t < NT; ++t) {
    const int cur = t & 1;
    if (t + 1 < NT) stage(cur ^ 1, (t + 1) * BK);   // prefetch next tile

#pragma unroll
    for (int kk = 0; kk < 2; ++kk) {
      bf16x8 af[WR], bfr[WC];
#pragma unroll
      for (int mf = 0; mf < WR; ++mf) {
        const int r = wm * (BM / WM) + mf * 16 + l15;
        const int c = ((kk * 4 + l4) ^ (r & 7)) * 8;
        af[mf] = *reinterpret_cast<const bf16x8*>(&a_sh[cur][r * BK + c]);
      }
#pragma unroll
      for (int nf = 0; nf < WC; ++nf) {
        const int r = wn * (BN / WN) + nf * 16 + l15;
        const int c = ((kk * 4 + l4) ^ (r & 7)) * 8;
        bfr[nf] = *reinterpret_cast<const bf16x8*>(&b_sh[cur][r * BK + c]);
      }
#pragma unroll
      for (int mf = 0; mf < WR; ++mf)
#pragma unroll
        for (int nf = 0; nf < WC; ++nf)
          acc[mf][nf] = __builtin_amdgcn_mfma_f32_16x16x32_bf16(af[mf], bfr[nf], acc[mf][nf], 0, 0, 0);
    }

    asm volatile("s_waitcnt vmcnt(0)" ::: "memory");  // prefetch landed
    __syncthreads();                                  // buf[cur] consumed by all
  }

#pragma unroll
  for (int mf = 0; mf < WR; ++mf) {
#pragma unroll
    for (int nf = 0; nf < WC; ++nf) {
#pragma unroll
      for (int r = 0; r < 4; ++r) {
        const long row = bm0 + wm * (BM / WM) + mf * 16 + 4 * l4 + r;
        const long col = bn0 + wn * (BN / WN) + nf * 16 + l15;
        float v = acc[mf][nf][r] + bias[col];
        if constexpr (MODE == 0) {
          const int n = (int)col;
          const int which = n >> 10, rem2 = n & 1023;
          const int head = rem2 >> 6, d = rem2 & 63;
          const int b = (int)(row >> 10), s = (int)(row & 1023);
          const unsigned short bv = f2bf(v);
          const long qi = ((long)(b * 16 + head) * 1024 + s) * 64 + d;
          if (which == 0)      outb[qi] = bv;
          else if (which == 1) kbuf[qi] = bv;
          else                 vtbuf[((long)(b * 16 + head) * 64 + d) * 1024 + s] = bv;
        } else if constexpr (MODE == 1) {
          outf[row * N + col] = v + res[row * N + col];
        } else if constexpr (MODE == 2) {
          float mv;
          if (v > 20.f) mv = v;
          else { const float t2 = __expf(v); const float u = t2 * t2 + 2.f * t2;
                 mv = v * u / (u + 2.f); }
          outb[row * (long)N + col] = f2bf(mv);
        } else {
          outf[row * N + col] = v + res[row * N + col];
        }
      }
    }
  }
}

// ---------------------------------------------------------------------------
// Flash attention (R6 structure): grid (S/128, B*H), 8 waves x 16 q-rows.
// Shuffle-free softmax; bias ping-pong register prefetch; dbuf gload_lds K/V.
// ---------------------------------------------------------------------------
__global__ __launch_bounds__(512, 2) void attn_kernel(
    const unsigned short* __restrict__ qb, const unsigned short* __restrict__ kb,
    const unsigned short* __restrict__ vtb, const float* __restrict__ bias,
    unsigned short* __restrict__ ctx) {
  constexpr int S = 1024;
  __shared__ unsigned short k_sh[2][64 * 64];
  __shared__ unsigned short vt_sh[2][64 * 64];
  __shared__ unsigned short p_sh[8][16 * 72];

  const int bh = blockIdx.y;
  const int q0 = blockIdx.x * 128;
  const int tid = threadIdx.x, wave = tid >> 6, lane = tid & 63;
  const int l15 = lane & 15, l4 = lane >> 4;

  const long qbase = ((long)bh * S + q0 + wave * 16 + l15) * 64;
  const bf16x8 qf0 = *reinterpret_cast<const bf16x8*>(qb + qbase + 8 * l4);
  const bf16x8 qf1 = *reinterpret_cast<const bf16x8*>(qb + qbase + 8 * l4 + 32);

  const int sr8 = lane >> 3;
  const int gchunk = ((lane & 7) ^ sr8) * 8;
  const long kbase = (long)bh * S * 64;
  const long vbase = (long)bh * 64 * S;

  const float* bB = bias + ((long)bh * S + q0 + wave * 16 + 4 * l4) * S + l15;

  f32x4 oacc[4] = {};
  float lacc[4] = {};
  float ba[4][4], bb2[4][4];

  auto stageKV = [&](int kv, int buf) {
    const int r = wave * 8;
    gload16(kb + kbase + (long)(kv + r + sr8) * 64 + gchunk, &k_sh[buf][r * 64]);
    gload16(vtb + vbase + (long)(r + sr8) * S + kv + gchunk, &vt_sh[buf][r * 64]);
  };

  stageKV(0, 0);
#pragma unroll
  for (int r = 0; r < 4; ++r)
#pragma unroll
    for (int nf = 0; nf < 4; ++nf)
      ba[r][nf] = bB[(long)r * S + nf * 16];
  asm volatile("s_waitcnt vmcnt(0)" ::: "memory");
  __syncthreads();

#pragma unroll 1
  for (int tt = 0; tt < 8; ++tt) {
    const int t0 = 2 * tt;
#pragma unroll
    for (int half = 0; half < 2; ++half) {
      const int t = t0 + half;
      const int cur = half, nxt = half ^ 1;
      float (*bcur)[4] = half ? bb2 : ba;
      float (*bnxt)[4] = half ? ba : bb2;

      if (t < 15) stageKV((t + 1) * 64, nxt);

      f32x4 sc[4];
#pragma unroll
      for (int nf = 0; nf < 4; ++nf) {
        const int r = nf * 16 + l15;
        const bf16x8 kf0 = *reinterpret_cast<const bf16x8*>(
            &k_sh[cur][r * 64 + ((l4) ^ (r & 7)) * 8]);
        const bf16x8 kf1 = *reinterpret_cast<const bf16x8*>(
            &k_sh[cur][r * 64 + ((l4 + 4) ^ (r & 7)) * 8]);
        f32x4 z = {};
        z = __builtin_amdgcn_mfma_f32_16x16x32_bf16(qf0, kf0, z, 0, 0, 0);
        sc[nf] = __builtin_amdgcn_mfma_f32_16x16x32_bf16(qf1, kf1, z, 0, 0, 0);
      }

      if (t < 15) {
        const float* bn = bB + (t + 1) * 64;
#pragma unroll
        for (int r = 0; r < 4; ++r)
#pragma unroll
          for (int nf = 0; nf < 4; ++nf)
            bnxt[r][nf] = bn[(long)r * S + nf * 16];
      }

      float pv[4][4];
#pragma unroll
      for (int r = 0; r < 4; ++r) {
        float ls = 0.f;
#pragma unroll
        for (int nf = 0; nf < 4; ++nf) {
          const float p = __expf(sc[nf][r] * 0.125f + bcur[r][nf]);
          pv[nf][r] = p;
          ls += p;
        }
        lacc[r] += ls;
      }

#pragma unroll
      for (int nf = 0; nf < 4; ++nf)
#pragma unroll
        for (int r = 0; r < 4; ++r)
          p_sh[wave][(4 * l4 + r) * 72 + nf * 16 + l15] = f2bf(pv[nf][r]);

      const bf16x8 pa0 = *reinterpret_cast<const bf16x8*>(&p_sh[wave][l15 * 72 + 8 * l4]);
      const bf16x8 pa1 = *reinterpret_cast<const bf16x8*>(&p_sh[wave][l15 * 72 + 8 * l4 + 32]);
#pragma unroll
      for (int nf = 0; nf < 4; ++nf) {
        const int r = nf * 16 + l15;
        const bf16x8 vf0 = *reinterpret_cast<const bf16x8*>(
            &vt_sh[cur][r * 64 + ((l4) ^ (r & 7)) * 8]);
        const bf16x8 vf1 = *reinterpret_cast<const bf16x8*>(
            &vt_sh[cur][r * 64 + ((l4 + 4) ^ (r & 7)) * 8]);
        oacc[nf] = __builtin_amdgcn_mfma_f32_16x16x32_bf16(pa0, vf0, oacc[nf], 0, 0, 0);
        oacc[nf] = __builtin_amdgcn_mfma_f32_16x16x32_bf16(pa1, vf1, oacc[nf], 0, 0, 0);
      }

      asm volatile("s_waitcnt vmcnt(0)" ::: "memory");
      __syncthreads();
    }
  }

#pragma unroll
  for (int r = 0; r < 4; ++r) {
    float v = lacc[r];
    v += __shfl_xor(v, 1);
    v += __shfl_xor(v, 2);
    v += __shfl_xor(v, 4);
    v += __shfl_xor(v, 8);
    lacc[r] = 1.f / v;
  }

  const int b = bh >> 4, h = bh & 15;
#pragma unroll
  for (int nf = 0; nf < 4; ++nf)
#pragma unroll
    for (int r = 0; r < 4; ++r) {
      const long s = q0 + wave * 16 + 4 * l4 + r;
      const long col = h * 64 + nf * 16 + l15;
      ctx[((long)b * S + s) * 1024 + col] = f2bf(oacc[nf][r] * lacc[r]);
    }
}

// ---------------------------------------------------------------------------
extern "C" void kernel_launch(void* const* d_in, const int* in_sizes, int n_in,
                              void* d_out, int out_size, void* d_ws, size_t ws_size,
                              hipStream_t stream) {
  const float* x    = (const float*)d_in[0];
  const float* ab   = (const float*)d_in[1];
  const float* ln1g = (const float*)d_in[2];
  const float* ln1b = (const float*)d_in[3];
  const float* Wqkv = (const float*)d_in[4];
  const float* bqkv = (const float*)d_in[5];
  const float* Wo   = (const float*)d_in[6];
  const float* bo   = (const float*)d_in[7];
  const float* ln2g = (const float*)d_in[8];
  const float* ln2b = (const float*)d_in[9];
  const float* W1   = (const float*)d_in[10];
  const float* b1   = (const float*)d_in[11];
  const float* W2   = (const float*)d_in[12];
  const float* b2   = (const float*)d_in[13];
  float* out = (float*)d_out;

  char* ws = (char*)d_ws;
  size_t off = 0;
  auto alloc = [&](size_t bytes) {
    char* p = ws + off;
    off += (bytes + 255) & ~(size_t)255;
    return p;
  };
  unsigned short* wqkv_t = (unsigned short*)alloc((size_t)3072 * 1024 * 2);
  unsigned short* wo_t   = (unsigned short*)alloc((size_t)1024 * 1024 * 2);
  unsigned short* w1_t   = (unsigned short*)alloc((size_t)4096 * 1024 * 2);
  unsigned short* w2_t   = (unsigned short*)alloc((size_t)4096 * 1024 * 2);
  unsigned short* h1     = (unsigned short*)alloc((size_t)2048 * 1024 * 2);  // ffn1 aliases h1..vtbuf
  unsigned short* qbuf   = (unsigned short*)alloc((size_t)2048 * 1024 * 2);
  unsigned short* kbuf   = (unsigned short*)alloc((size_t)2048 * 1024 * 2);
  unsigned short* vtbuf  = (unsigned short*)alloc((size_t)2048 * 1024 * 2);
  unsigned short* ctx    = (unsigned short*)alloc((size_t)2048 * 1024 * 2);
  unsigned short* h2     = (unsigned short*)alloc((size_t)2048 * 1024 * 2);
  float*          r1     = (float*)alloc((size_t)2048 * 1024 * 4);
  unsigned short* ffn1   = h1;  // 16MB alias over h1/qbuf/kbuf/vtbuf (dead after attn)
  (void)ws_size; (void)in_sizes; (void)n_in; (void)out_size;

  convert_ln<<<14336, dim3(32, 8), 0, stream>>>(Wqkv, Wo, W1, W2, x, ln1g, ln1b,
                                                wqkv_t, wo_t, w1_t, w2_t, h1);

  gemm_kernel<0, 128, 128><<<384, 256, 0, stream>>>(h1, wqkv_t, bqkv, 2048, 3072, 1024,
                                                    nullptr, nullptr, qbuf, kbuf, vtbuf);

  attn_kernel<<<dim3(8, 32), 512, 0, stream>>>(qbuf, kbuf, vtbuf, ab, ctx);

  gemm_kernel<1, 64, 64><<<512, 256, 0, stream>>>(ctx, wo_t, bo, 2048, 1024, 1024,
                                                  r1, x, nullptr, nullptr, nullptr);

  ln_kernel<<<2048, 256, 0, stream>>>(r1, ln2g, ln2b, h2);

  gemm_kernel<2, 128, 128><<<512, 256, 0, stream>>>(h2, w1_t, b1, 2048, 4096, 1024,
                                                    nullptr, nullptr, ffn1, nullptr, nullptr);

  gemm_kernel<3, 64, 64><<<512, 256, 0, stream>>>(ffn1, w2_t, b2, 2048, 1024, 4096,
                                                  out, r1, nullptr, nullptr, nullptr);
}

// Round 10
// 163.677 us; speedup vs baseline: 1.1789x; 1.0274x over previous
//
#include <hip/hip_runtime.h>

// ---------------------------------------------------------------------------
// TransformerBlock: LN1 -> QKV -> attn(+bias, softmax) -> Wo(+x) -> LN2
//                   -> FFN1(+mish) -> FFN2(+residual)
// fp32 I/O, bf16 MFMA GEMMs (16x16x32), flash-style attention.
// R10: attn XCD-locality remap (each XCD owns 4 heads -> K/V L2-resident);
//      QKV BN=96 (512 blocks = exactly 2/CU, even wave balance). Rest = R9.
// ---------------------------------------------------------------------------

typedef __attribute__((ext_vector_type(8))) __bf16 bf16x8;
typedef __attribute__((ext_vector_type(4))) float  f32x4;

__device__ __forceinline__ unsigned short f2bf(float f) {
  unsigned int u = __builtin_bit_cast(unsigned int, f);
  u += 0x7fffu + ((u >> 16) & 1u);          // round-to-nearest-even
  return (unsigned short)(u >> 16);
}

__device__ __forceinline__ void gload16(const void* g, void* l) {
  __builtin_amdgcn_global_load_lds(
      (const __attribute__((address_space(1))) void*)g,
      (__attribute__((address_space(3))) void*)l, 16, 0, 0);
}

// ---------------------------------------------------------------------------
// Fused: 4 weight converts fp32(KxN)->bf16 transposed(NxK)  +  LN1.
// blocks 0..12287: converts; 12288..14335: LN1 rows.
// ---------------------------------------------------------------------------
__global__ __launch_bounds__(256) void convert_ln(
    const float* __restrict__ Wqkv, const float* __restrict__ Wo,
    const float* __restrict__ W1, const float* __restrict__ W2,
    const float* __restrict__ x, const float* __restrict__ g,
    const float* __restrict__ bln,
    unsigned short* __restrict__ wqkv_t, unsigned short* __restrict__ wo_t,
    unsigned short* __restrict__ w1_t, unsigned short* __restrict__ w2_t,
    unsigned short* __restrict__ h1) {
  __shared__ float tile[32][33];
  __shared__ float ps[4], ps2[4];
  const int id = blockIdx.x;
  const int tx = threadIdx.x, ty = threadIdx.y;   // (32,8)

  if (id < 12288) {
    const float* W; unsigned short* Wt; int K, N, t;
    if (id < 3072)      { W = Wqkv; Wt = wqkv_t; K = 1024; N = 3072; t = id; }
    else if (id < 4096) { W = Wo;   Wt = wo_t;   K = 1024; N = 1024; t = id - 3072; }
    else if (id < 8192) { W = W1;   Wt = w1_t;   K = 1024; N = 4096; t = id - 4096; }
    else                { W = W2;   Wt = w2_t;   K = 4096; N = 1024; t = id - 8192; }
    const int nx = N >> 5;
    const int n0 = (t % nx) * 32, k0 = (t / nx) * 32;
#pragma unroll
    for (int r = 0; r < 4; ++r)
      tile[ty + 8 * r][tx] = W[(size_t)(k0 + ty + 8 * r) * N + n0 + tx];
    __syncthreads();
#pragma unroll
    for (int r = 0; r < 4; ++r)
      Wt[(size_t)(n0 + ty + 8 * r) * K + k0 + tx] = f2bf(tile[tx][ty + 8 * r]);
  } else {
    const int row = id - 12288;
    const int t = ty * 32 + tx;
    const float4 v = reinterpret_cast<const float4*>(x + (size_t)row * 1024)[t];
    float s  = v.x + v.y + v.z + v.w;
    float s2 = v.x * v.x + v.y * v.y + v.z * v.z + v.w * v.w;
#pragma unroll
    for (int m = 1; m < 64; m <<= 1) { s += __shfl_xor(s, m); s2 += __shfl_xor(s2, m); }
    const int wv = t >> 6;
    if ((t & 63) == 0) { ps[wv] = s; ps2[wv] = s2; }
    __syncthreads();
    float ts = 0.f, ts2 = 0.f;
#pragma unroll
    for (int i = 0; i < 4; ++i) { ts += ps[i]; ts2 += ps2[i]; }
    const float mu = ts * (1.f / 1024.f);
    const float var = ts2 * (1.f / 1024.f) - mu * mu;
    const float rstd = rsqrtf(var + 1e-5f);
    const float4 gg = reinterpret_cast<const float4*>(g)[t];
    const float4 bb = reinterpret_cast<const float4*>(bln)[t];
    ushort4 ov;
    ov.x = f2bf((v.x - mu) * rstd * gg.x + bb.x);
    ov.y = f2bf((v.y - mu) * rstd * gg.y + bb.y);
    ov.z = f2bf((v.z - mu) * rstd * gg.z + bb.z);
    ov.w = f2bf((v.w - mu) * rstd * gg.w + bb.w);
    *reinterpret_cast<ushort4*>(h1 + (size_t)row * 1024 + t * 4) = ov;
  }
}

// ---------------------------------------------------------------------------
// LayerNorm (standalone, for LN2).
// ---------------------------------------------------------------------------
__global__ __launch_bounds__(256) void ln_kernel(const float* __restrict__ in,
                                                 const float* __restrict__ g,
                                                 const float* __restrict__ b,
                                                 unsigned short* __restrict__ out) {
  const int row = blockIdx.x;
  const int t = threadIdx.x;
  const float4 v = reinterpret_cast<const float4*>(in + (size_t)row * 1024)[t];
  float s  = v.x + v.y + v.z + v.w;
  float s2 = v.x * v.x + v.y * v.y + v.z * v.z + v.w * v.w;
#pragma unroll
  for (int m = 1; m < 64; m <<= 1) { s += __shfl_xor(s, m); s2 += __shfl_xor(s2, m); }
  __shared__ float ps[4], ps2[4];
  const int wv = t >> 6;
  if ((t & 63) == 0) { ps[wv] = s; ps2[wv] = s2; }
  __syncthreads();
  float ts = 0.f, ts2 = 0.f;
#pragma unroll
  for (int i = 0; i < 4; ++i) { ts += ps[i]; ts2 += ps2[i]; }
  const float mu = ts * (1.f / 1024.f);
  const float var = ts2 * (1.f / 1024.f) - mu * mu;
  const float rstd = rsqrtf(var + 1e-5f);
  const float4 gg = reinterpret_cast<const float4*>(g)[t];
  const float4 bb = reinterpret_cast<const float4*>(b)[t];
  ushort4 ov;
  ov.x = f2bf((v.x - mu) * rstd * gg.x + bb.x);
  ov.y = f2bf((v.y - mu) * rstd * gg.y + bb.y);
  ov.z = f2bf((v.z - mu) * rstd * gg.z + bb.z);
  ov.w = f2bf((v.w - mu) * rstd * gg.w + bb.w);
  *reinterpret_cast<ushort4*>(out + (size_t)row * 1024 + t * 4) = ov;
}

// ---------------------------------------------------------------------------
// GEMM (R6 loop, R9 order): C = A @ Bt^T + bias. 2-stage prefetch, one
// vmcnt(0)+barrier per K-step, XOR chunk swizzle, XCD-chunked 2-D blocking.
// BN may be 64/96/128; BM 64/128. Requires GY%8==0.
// ---------------------------------------------------------------------------
template <int MODE, int BM, int BN>
__global__ __launch_bounds__(256, 2) void gemm_kernel(
    const unsigned short* __restrict__ A, const unsigned short* __restrict__ Bt,
    const float* __restrict__ bias, int M, int N, int K,
    float* __restrict__ outf, const float* __restrict__ res,
    unsigned short* __restrict__ outb,
    unsigned short* __restrict__ kbuf, unsigned short* __restrict__ vtbuf) {
  constexpr int BK = 64;
  constexpr int WN = (BN >= 96 || BM == 64) ? 2 : 1;
  constexpr int WM = 4 / WN;
  constexpr int WR = BM / WM / 16;
  constexpr int WC = BN / WN / 16;
  constexpr int AI = BM / 32, BI = BN / 32;
  __shared__ unsigned short a_sh[2][BM * BK];
  __shared__ unsigned short b_sh[2][BN * BK];

  const int tid = threadIdx.x;
  const int wave = tid >> 6, lane = tid & 63;
  const int wm = wave / WN, wn = wave % WN;
  const int l15 = lane & 15, l4 = lane >> 4;

  const int nwg = gridDim.x, cpx = nwg >> 3;
  const int swz = (blockIdx.x & 7) * cpx + (blockIdx.x >> 3);
  const int GX = N / BN;
  const int sr  = swz / (8 * GX);
  const int rem = swz % (8 * GX);
  const long bm0 = (long)(sr * 8 + (rem & 7)) * BM;
  const long bn0 = (long)(rem >> 3) * BN;

  const int sr8 = lane >> 3;
  const int gc  = ((lane & 7) ^ sr8) * 8;       // inverse-swizzled source chunk

  const unsigned short* agp[AI];
  const unsigned short* bgp[BI];
  int aoff[AI], boff[BI];
#pragma unroll
  for (int i = 0; i < AI; ++i) {
    const int r = wave * (BM / 4) + i * 8;
    agp[i] = A + (bm0 + r + sr8) * (long)K + gc;
    aoff[i] = r * BK;
  }
#pragma unroll
  for (int i = 0; i < BI; ++i) {
    const int r = wave * (BN / 4) + i * 8;
    bgp[i] = Bt + (bn0 + r + sr8) * (long)K + gc;
    boff[i] = r * BK;
  }

  auto stage = [&](int buf, int k0) {
#pragma unroll
    for (int i = 0; i < AI; ++i) gload16(agp[i] + k0, &a_sh[buf][aoff[i]]);
#pragma unroll
    for (int i = 0; i < BI; ++i) gload16(bgp[i] + k0, &b_sh[buf][boff[i]]);
  };

  f32x4 acc[WR][WC] = {};

  stage(0, 0);
  asm volatile("s_waitcnt vmcnt(0)" ::: "memory");
  __syncthreads();

  const int NT = K / BK;
  for (int t = 0; t < NT; ++t) {
    const int cur = t & 1;
    if (t + 1 < NT) stage(cur ^ 1, (t + 1) * BK);   // prefetch next tile

#pragma unroll
    for (int kk = 0; kk < 2; ++kk) {
      bf16x8 af[WR], bfr[WC];
#pragma unroll
      for (int mf = 0; mf < WR; ++mf) {
        const int r = wm * (BM / WM) + mf * 16 + l15;
        const int c = ((kk * 4 + l4) ^ (r & 7)) * 8;
        af[mf] = *reinterpret_cast<const bf16x8*>(&a_sh[cur][r * BK + c]);
      }
#pragma unroll
      for (int nf = 0; nf < WC; ++nf) {
        const int r = wn * (BN / WN) + nf * 16 + l15;
        const int c = ((kk * 4 + l4) ^ (r & 7)) * 8;
        bfr[nf] = *reinterpret_cast<const bf16x8*>(&b_sh[cur][r * BK + c]);
      }
#pragma unroll
      for (int mf = 0; mf < WR; ++mf)
#pragma unroll
        for (int nf = 0; nf < WC; ++nf)
          acc[mf][nf] = __builtin_amdgcn_mfma_f32_16x16x32_bf16(af[mf], bfr[nf], acc[mf][nf], 0, 0, 0);
    }

    asm volatile("s_waitcnt vmcnt(0)" ::: "memory");  // prefetch landed
    __syncthreads();                                  // buf[cur] consumed by all
  }

#pragma unroll
  for (int mf = 0; mf < WR; ++mf) {
#pragma unroll
    for (int nf = 0; nf < WC; ++nf) {
#pragma unroll
      for (int r = 0; r < 4; ++r) {
        const long row = bm0 + wm * (BM / WM) + mf * 16 + 4 * l4 + r;
        const long col = bn0 + wn * (BN / WN) + nf * 16 + l15;
        float v = acc[mf][nf][r] + bias[col];
        if constexpr (MODE == 0) {
          const int n = (int)col;
          const int which = n >> 10, rem2 = n & 1023;
          const int head = rem2 >> 6, d = rem2 & 63;
          const int b = (int)(row >> 10), s = (int)(row & 1023);
          const unsigned short bv = f2bf(v);
          const long qi = ((long)(b * 16 + head) * 1024 + s) * 64 + d;
          if (which == 0)      outb[qi] = bv;
          else if (which == 1) kbuf[qi] = bv;
          else                 vtbuf[((long)(b * 16 + head) * 64 + d) * 1024 + s] = bv;
        } else if constexpr (MODE == 1) {
          outf[row * N + col] = v + res[row * N + col];
        } else if constexpr (MODE == 2) {
          float mv;
          if (v > 20.f) mv = v;
          else { const float t2 = __expf(v); const float u = t2 * t2 + 2.f * t2;
                 mv = v * u / (u + 2.f); }
          outb[row * (long)N + col] = f2bf(mv);
        } else {
          outf[row * N + col] = v + res[row * N + col];
        }
      }
    }
  }
}

// ---------------------------------------------------------------------------
// Flash attention (R6 structure + R10 XCD remap): 1-D grid 256.
// id -> XCD c = id&7 owns heads bh in {4c..4c+3}; all 8 q-blocks of a head
// run on the same XCD concurrently -> K/V L2-resident.
// ---------------------------------------------------------------------------
__global__ __launch_bounds__(512, 2) void attn_kernel(
    const unsigned short* __restrict__ qb, const unsigned short* __restrict__ kb,
    const unsigned short* __restrict__ vtb, const float* __restrict__ bias,
    unsigned short* __restrict__ ctx) {
  constexpr int S = 1024;
  __shared__ unsigned short k_sh[2][64 * 64];
  __shared__ unsigned short vt_sh[2][64 * 64];
  __shared__ unsigned short p_sh[8][16 * 72];

  const int id = blockIdx.x;
  const int c = id & 7, p = id >> 3;
  const int bh = c * 4 + (p >> 3);
  const int q0 = (p & 7) * 128;
  const int tid = threadIdx.x, wave = tid >> 6, lane = tid & 63;
  const int l15 = lane & 15, l4 = lane >> 4;

  const long qbase = ((long)bh * S + q0 + wave * 16 + l15) * 64;
  const bf16x8 qf0 = *reinterpret_cast<const bf16x8*>(qb + qbase + 8 * l4);
  const bf16x8 qf1 = *reinterpret_cast<const bf16x8*>(qb + qbase + 8 * l4 + 32);

  const int sr8 = lane >> 3;
  const int gchunk = ((lane & 7) ^ sr8) * 8;
  const long kbase = (long)bh * S * 64;
  const long vbase = (long)bh * 64 * S;

  const float* bB = bias + ((long)bh * S + q0 + wave * 16 + 4 * l4) * S + l15;

  f32x4 oacc[4] = {};
  float lacc[4] = {};
  float ba[4][4], bb2[4][4];

  auto stageKV = [&](int kv, int buf) {
    const int r = wave * 8;
    gload16(kb + kbase + (long)(kv + r + sr8) * 64 + gchunk, &k_sh[buf][r * 64]);
    gload16(vtb + vbase + (long)(r + sr8) * S + kv + gchunk, &vt_sh[buf][r * 64]);
  };

  stageKV(0, 0);
#pragma unroll
  for (int r = 0; r < 4; ++r)
#pragma unroll
    for (int nf = 0; nf < 4; ++nf)
      ba[r][nf] = bB[(long)r * S + nf * 16];
  asm volatile("s_waitcnt vmcnt(0)" ::: "memory");
  __syncthreads();

#pragma unroll 1
  for (int tt = 0; tt < 8; ++tt) {
    const int t0 = 2 * tt;
#pragma unroll
    for (int half = 0; half < 2; ++half) {
      const int t = t0 + half;
      const int cur = half, nxt = half ^ 1;
      float (*bcur)[4] = half ? bb2 : ba;
      float (*bnxt)[4] = half ? ba : bb2;

      if (t < 15) stageKV((t + 1) * 64, nxt);

      f32x4 sc[4];
#pragma unroll
      for (int nf = 0; nf < 4; ++nf) {
        const int r = nf * 16 + l15;
        const bf16x8 kf0 = *reinterpret_cast<const bf16x8*>(
            &k_sh[cur][r * 64 + ((l4) ^ (r & 7)) * 8]);
        const bf16x8 kf1 = *reinterpret_cast<const bf16x8*>(
            &k_sh[cur][r * 64 + ((l4 + 4) ^ (r & 7)) * 8]);
        f32x4 z = {};
        z = __builtin_amdgcn_mfma_f32_16x16x32_bf16(qf0, kf0, z, 0, 0, 0);
        sc[nf] = __builtin_amdgcn_mfma_f32_16x16x32_bf16(qf1, kf1, z, 0, 0, 0);
      }

      if (t < 15) {
        const float* bn = bB + (t + 1) * 64;
#pragma unroll
        for (int r = 0; r < 4; ++r)
#pragma unroll
          for (int nf = 0; nf < 4; ++nf)
            bnxt[r][nf] = bn[(long)r * S + nf * 16];
      }

      float pv[4][4];
#pragma unroll
      for (int r = 0; r < 4; ++r) {
        float ls = 0.f;
#pragma unroll
        for (int nf = 0; nf < 4; ++nf) {
          const float p = __expf(sc[nf][r] * 0.125f + bcur[r][nf]);
          pv[nf][r] = p;
          ls += p;
        }
        lacc[r] += ls;
      }

#pragma unroll
      for (int nf = 0; nf < 4; ++nf)
#pragma unroll
        for (int r = 0; r < 4; ++r)
          p_sh[wave][(4 * l4 + r) * 72 + nf * 16 + l15] = f2bf(pv[nf][r]);

      const bf16x8 pa0 = *reinterpret_cast<const bf16x8*>(&p_sh[wave][l15 * 72 + 8 * l4]);
      const bf16x8 pa1 = *reinterpret_cast<const bf16x8*>(&p_sh[wave][l15 * 72 + 8 * l4 + 32]);
#pragma unroll
      for (int nf = 0; nf < 4; ++nf) {
        const int r = nf * 16 + l15;
        const bf16x8 vf0 = *reinterpret_cast<const bf16x8*>(
            &vt_sh[cur][r * 64 + ((l4) ^ (r & 7)) * 8]);
        const bf16x8 vf1 = *reinterpret_cast<const bf16x8*>(
            &vt_sh[cur][r * 64 + ((l4 + 4) ^ (r & 7)) * 8]);
        oacc[nf] = __builtin_amdgcn_mfma_f32_16x16x32_bf16(pa0, vf0, oacc[nf], 0, 0, 0);
        oacc[nf] = __builtin_amdgcn_mfma_f32_16x16x32_bf16(pa1, vf1, oacc[nf], 0, 0, 0);
      }

      asm volatile("s_waitcnt vmcnt(0)" ::: "memory");
      __syncthreads();
    }
  }

#pragma unroll
  for (int r = 0; r < 4; ++r) {
    float v = lacc[r];
    v += __shfl_xor(v, 1);
    v += __shfl_xor(v, 2);
    v += __shfl_xor(v, 4);
    v += __shfl_xor(v, 8);
    lacc[r] = 1.f / v;
  }

  const int b = bh >> 4, h = bh & 15;
#pragma unroll
  for (int nf = 0; nf < 4; ++nf)
#pragma unroll
    for (int r = 0; r < 4; ++r) {
      const long s = q0 + wave * 16 + 4 * l4 + r;
      const long col = h * 64 + nf * 16 + l15;
      ctx[((long)b * S + s) * 1024 + col] = f2bf(oacc[nf][r] * lacc[r]);
    }
}

// ---------------------------------------------------------------------------
extern "C" void kernel_launch(void* const* d_in, const int* in_sizes, int n_in,
                              void* d_out, int out_size, void* d_ws, size_t ws_size,
                              hipStream_t stream) {
  const float* x    = (const float*)d_in[0];
  const float* ab   = (const float*)d_in[1];
  const float* ln1g = (const float*)d_in[2];
  const float* ln1b = (const float*)d_in[3];
  const float* Wqkv = (const float*)d_in[4];
  const float* bqkv = (const float*)d_in[5];
  const float* Wo   = (const float*)d_in[6];
  const float* bo   = (const float*)d_in[7];
  const float* ln2g = (const float*)d_in[8];
  const float* ln2b = (const float*)d_in[9];
  const float* W1   = (const float*)d_in[10];
  const float* b1   = (const float*)d_in[11];
  const float* W2   = (const float*)d_in[12];
  const float* b2   = (const float*)d_in[13];
  float* out = (float*)d_out;

  char* ws = (char*)d_ws;
  size_t off = 0;
  auto alloc = [&](size_t bytes) {
    char* p = ws + off;
    off += (bytes + 255) & ~(size_t)255;
    return p;
  };
  unsigned short* wqkv_t = (unsigned short*)alloc((size_t)3072 * 1024 * 2);
  unsigned short* wo_t   = (unsigned short*)alloc((size_t)1024 * 1024 * 2);
  unsigned short* w1_t   = (unsigned short*)alloc((size_t)4096 * 1024 * 2);
  unsigned short* w2_t   = (unsigned short*)alloc((size_t)4096 * 1024 * 2);
  unsigned short* h1     = (unsigned short*)alloc((size_t)2048 * 1024 * 2);  // ffn1 aliases h1..vtbuf
  unsigned short* qbuf   = (unsigned short*)alloc((size_t)2048 * 1024 * 2);
  unsigned short* kbuf   = (unsigned short*)alloc((size_t)2048 * 1024 * 2);
  unsigned short* vtbuf  = (unsigned short*)alloc((size_t)2048 * 1024 * 2);
  unsigned short* ctx    = (unsigned short*)alloc((size_t)2048 * 1024 * 2);
  unsigned short* h2     = (unsigned short*)alloc((size_t)2048 * 1024 * 2);
  float*          r1     = (float*)alloc((size_t)2048 * 1024 * 4);
  unsigned short* ffn1   = h1;  // 16MB alias over h1/qbuf/kbuf/vtbuf (dead after attn)
  (void)ws_size; (void)in_sizes; (void)n_in; (void)out_size;

  convert_ln<<<14336, dim3(32, 8), 0, stream>>>(Wqkv, Wo, W1, W2, x, ln1g, ln1b,
                                                wqkv_t, wo_t, w1_t, w2_t, h1);

  gemm_kernel<0, 128, 96><<<512, 256, 0, stream>>>(h1, wqkv_t, bqkv, 2048, 3072, 1024,
                                                   nullptr, nullptr, qbuf, kbuf, vtbuf);

  attn_kernel<<<256, 512, 0, stream>>>(qbuf, kbuf, vtbuf, ab, ctx);

  gemm_kernel<1, 64, 64><<<512, 256, 0, stream>>>(ctx, wo_t, bo, 2048, 1024, 1024,
                                                  r1, x, nullptr, nullptr, nullptr);

  ln_kernel<<<2048, 256, 0, stream>>>(r1, ln2g, ln2b, h2);

  gemm_kernel<2, 128, 128><<<512, 256, 0, stream>>>(h2, w1_t, b1, 2048, 4096, 1024,
                                                    nullptr, nullptr, ffn1, nullptr, nullptr);

  gemm_kernel<3, 64, 64><<<512, 256, 0, stream>>>(ffn1, w2_t, b2, 2048, 1024, 4096,
                                                  out, r1, nullptr, nullptr, nullptr);
}

// Round 11
// 159.426 us; speedup vs baseline: 1.2103x; 1.0267x over previous
//
#include <hip/hip_runtime.h>

// ---------------------------------------------------------------------------
// TransformerBlock: LN1 -> QKV -> attn(+bias, softmax) -> Wo(+x) -> LN2
//                   -> FFN1(+mish) -> FFN2(+residual)
// fp32 I/O, bf16 MFMA GEMMs (16x16x32), flash-style attention.
// R11: attn counted drain vmcnt(16) (bias stream stays in flight across
//      barriers) + 2-deep bias register prefetch. Rest = R10.
// ---------------------------------------------------------------------------

typedef __attribute__((ext_vector_type(8))) __bf16 bf16x8;
typedef __attribute__((ext_vector_type(4))) float  f32x4;

__device__ __forceinline__ unsigned short f2bf(float f) {
  unsigned int u = __builtin_bit_cast(unsigned int, f);
  u += 0x7fffu + ((u >> 16) & 1u);          // round-to-nearest-even
  return (unsigned short)(u >> 16);
}

__device__ __forceinline__ void gload16(const void* g, void* l) {
  __builtin_amdgcn_global_load_lds(
      (const __attribute__((address_space(1))) void*)g,
      (__attribute__((address_space(3))) void*)l, 16, 0, 0);
}

// ---------------------------------------------------------------------------
// Fused: 4 weight converts fp32(KxN)->bf16 transposed(NxK)  +  LN1.
// blocks 0..12287: converts; 12288..14335: LN1 rows.
// ---------------------------------------------------------------------------
__global__ __launch_bounds__(256) void convert_ln(
    const float* __restrict__ Wqkv, const float* __restrict__ Wo,
    const float* __restrict__ W1, const float* __restrict__ W2,
    const float* __restrict__ x, const float* __restrict__ g,
    const float* __restrict__ bln,
    unsigned short* __restrict__ wqkv_t, unsigned short* __restrict__ wo_t,
    unsigned short* __restrict__ w1_t, unsigned short* __restrict__ w2_t,
    unsigned short* __restrict__ h1) {
  __shared__ float tile[32][33];
  __shared__ float ps[4], ps2[4];
  const int id = blockIdx.x;
  const int tx = threadIdx.x, ty = threadIdx.y;   // (32,8)

  if (id < 12288) {
    const float* W; unsigned short* Wt; int K, N, t;
    if (id < 3072)      { W = Wqkv; Wt = wqkv_t; K = 1024; N = 3072; t = id; }
    else if (id < 4096) { W = Wo;   Wt = wo_t;   K = 1024; N = 1024; t = id - 3072; }
    else if (id < 8192) { W = W1;   Wt = w1_t;   K = 1024; N = 4096; t = id - 4096; }
    else                { W = W2;   Wt = w2_t;   K = 4096; N = 1024; t = id - 8192; }
    const int nx = N >> 5;
    const int n0 = (t % nx) * 32, k0 = (t / nx) * 32;
#pragma unroll
    for (int r = 0; r < 4; ++r)
      tile[ty + 8 * r][tx] = W[(size_t)(k0 + ty + 8 * r) * N + n0 + tx];
    __syncthreads();
#pragma unroll
    for (int r = 0; r < 4; ++r)
      Wt[(size_t)(n0 + ty + 8 * r) * K + k0 + tx] = f2bf(tile[tx][ty + 8 * r]);
  } else {
    const int row = id - 12288;
    const int t = ty * 32 + tx;
    const float4 v = reinterpret_cast<const float4*>(x + (size_t)row * 1024)[t];
    float s  = v.x + v.y + v.z + v.w;
    float s2 = v.x * v.x + v.y * v.y + v.z * v.z + v.w * v.w;
#pragma unroll
    for (int m = 1; m < 64; m <<= 1) { s += __shfl_xor(s, m); s2 += __shfl_xor(s2, m); }
    const int wv = t >> 6;
    if ((t & 63) == 0) { ps[wv] = s; ps2[wv] = s2; }
    __syncthreads();
    float ts = 0.f, ts2 = 0.f;
#pragma unroll
    for (int i = 0; i < 4; ++i) { ts += ps[i]; ts2 += ps2[i]; }
    const float mu = ts * (1.f / 1024.f);
    const float var = ts2 * (1.f / 1024.f) - mu * mu;
    const float rstd = rsqrtf(var + 1e-5f);
    const float4 gg = reinterpret_cast<const float4*>(g)[t];
    const float4 bb = reinterpret_cast<const float4*>(bln)[t];
    ushort4 ov;
    ov.x = f2bf((v.x - mu) * rstd * gg.x + bb.x);
    ov.y = f2bf((v.y - mu) * rstd * gg.y + bb.y);
    ov.z = f2bf((v.z - mu) * rstd * gg.z + bb.z);
    ov.w = f2bf((v.w - mu) * rstd * gg.w + bb.w);
    *reinterpret_cast<ushort4*>(h1 + (size_t)row * 1024 + t * 4) = ov;
  }
}

// ---------------------------------------------------------------------------
// LayerNorm (standalone, for LN2).
// ---------------------------------------------------------------------------
__global__ __launch_bounds__(256) void ln_kernel(const float* __restrict__ in,
                                                 const float* __restrict__ g,
                                                 const float* __restrict__ b,
                                                 unsigned short* __restrict__ out) {
  const int row = blockIdx.x;
  const int t = threadIdx.x;
  const float4 v = reinterpret_cast<const float4*>(in + (size_t)row * 1024)[t];
  float s  = v.x + v.y + v.z + v.w;
  float s2 = v.x * v.x + v.y * v.y + v.z * v.z + v.w * v.w;
#pragma unroll
  for (int m = 1; m < 64; m <<= 1) { s += __shfl_xor(s, m); s2 += __shfl_xor(s2, m); }
  __shared__ float ps[4], ps2[4];
  const int wv = t >> 6;
  if ((t & 63) == 0) { ps[wv] = s; ps2[wv] = s2; }
  __syncthreads();
  float ts = 0.f, ts2 = 0.f;
#pragma unroll
  for (int i = 0; i < 4; ++i) { ts += ps[i]; ts2 += ps2[i]; }
  const float mu = ts * (1.f / 1024.f);
  const float var = ts2 * (1.f / 1024.f) - mu * mu;
  const float rstd = rsqrtf(var + 1e-5f);
  const float4 gg = reinterpret_cast<const float4*>(g)[t];
  const float4 bb = reinterpret_cast<const float4*>(b)[t];
  ushort4 ov;
  ov.x = f2bf((v.x - mu) * rstd * gg.x + bb.x);
  ov.y = f2bf((v.y - mu) * rstd * gg.y + bb.y);
  ov.z = f2bf((v.z - mu) * rstd * gg.z + bb.z);
  ov.w = f2bf((v.w - mu) * rstd * gg.w + bb.w);
  *reinterpret_cast<ushort4*>(out + (size_t)row * 1024 + t * 4) = ov;
}

// ---------------------------------------------------------------------------
// GEMM (R6 loop, R9 order): C = A @ Bt^T + bias. 2-stage prefetch, one
// vmcnt(0)+barrier per K-step, XOR chunk swizzle, XCD-chunked 2-D blocking.
// ---------------------------------------------------------------------------
template <int MODE, int BM, int BN>
__global__ __launch_bounds__(256, 2) void gemm_kernel(
    const unsigned short* __restrict__ A, const unsigned short* __restrict__ Bt,
    const float* __restrict__ bias, int M, int N, int K,
    float* __restrict__ outf, const float* __restrict__ res,
    unsigned short* __restrict__ outb,
    unsigned short* __restrict__ kbuf, unsigned short* __restrict__ vtbuf) {
  constexpr int BK = 64;
  constexpr int WN = (BN >= 96 || BM == 64) ? 2 : 1;
  constexpr int WM = 4 / WN;
  constexpr int WR = BM / WM / 16;
  constexpr int WC = BN / WN / 16;
  constexpr int AI = BM / 32, BI = BN / 32;
  __shared__ unsigned short a_sh[2][BM * BK];
  __shared__ unsigned short b_sh[2][BN * BK];

  const int tid = threadIdx.x;
  const int wave = tid >> 6, lane = tid & 63;
  const int wm = wave / WN, wn = wave % WN;
  const int l15 = lane & 15, l4 = lane >> 4;

  const int nwg = gridDim.x, cpx = nwg >> 3;
  const int swz = (blockIdx.x & 7) * cpx + (blockIdx.x >> 3);
  const int GX = N / BN;
  const int sr  = swz / (8 * GX);
  const int rem = swz % (8 * GX);
  const long bm0 = (long)(sr * 8 + (rem & 7)) * BM;
  const long bn0 = (long)(rem >> 3) * BN;

  const int sr8 = lane >> 3;
  const int gc  = ((lane & 7) ^ sr8) * 8;       // inverse-swizzled source chunk

  const unsigned short* agp[AI];
  const unsigned short* bgp[BI];
  int aoff[AI], boff[BI];
#pragma unroll
  for (int i = 0; i < AI; ++i) {
    const int r = wave * (BM / 4) + i * 8;
    agp[i] = A + (bm0 + r + sr8) * (long)K + gc;
    aoff[i] = r * BK;
  }
#pragma unroll
  for (int i = 0; i < BI; ++i) {
    const int r = wave * (BN / 4) + i * 8;
    bgp[i] = Bt + (bn0 + r + sr8) * (long)K + gc;
    boff[i] = r * BK;
  }

  auto stage = [&](int buf, int k0) {
#pragma unroll
    for (int i = 0; i < AI; ++i) gload16(agp[i] + k0, &a_sh[buf][aoff[i]]);
#pragma unroll
    for (int i = 0; i < BI; ++i) gload16(bgp[i] + k0, &b_sh[buf][boff[i]]);
  };

  f32x4 acc[WR][WC] = {};

  stage(0, 0);
  asm volatile("s_waitcnt vmcnt(0)" ::: "memory");
  __syncthreads();

  const int NT = K / BK;
  for (int t = 0; t < NT; ++t) {
    const int cur = t & 1;
    if (t + 1 < NT) stage(cur ^ 1, (t + 1) * BK);   // prefetch next tile

#pragma unroll
    for (int kk = 0; kk < 2; ++kk) {
      bf16x8 af[WR], bfr[WC];
#pragma unroll
      for (int mf = 0; mf < WR; ++mf) {
        const int r = wm * (BM / WM) + mf * 16 + l15;
        const int c = ((kk * 4 + l4) ^ (r & 7)) * 8;
        af[mf] = *reinterpret_cast<const bf16x8*>(&a_sh[cur][r * BK + c]);
      }
#pragma unroll
      for (int nf = 0; nf < WC; ++nf) {
        const int r = wn * (BN / WN) + nf * 16 + l15;
        const int c = ((kk * 4 + l4) ^ (r & 7)) * 8;
        bfr[nf] = *reinterpret_cast<const bf16x8*>(&b_sh[cur][r * BK + c]);
      }
#pragma unroll
      for (int mf = 0; mf < WR; ++mf)
#pragma unroll
        for (int nf = 0; nf < WC; ++nf)
          acc[mf][nf] = __builtin_amdgcn_mfma_f32_16x16x32_bf16(af[mf], bfr[nf], acc[mf][nf], 0, 0, 0);
    }

    asm volatile("s_waitcnt vmcnt(0)" ::: "memory");  // prefetch landed
    __syncthreads();                                  // buf[cur] consumed by all
  }

#pragma unroll
  for (int mf = 0; mf < WR; ++mf) {
#pragma unroll
    for (int nf = 0; nf < WC; ++nf) {
#pragma unroll
      for (int r = 0; r < 4; ++r) {
        const long row = bm0 + wm * (BM / WM) + mf * 16 + 4 * l4 + r;
        const long col = bn0 + wn * (BN / WN) + nf * 16 + l15;
        float v = acc[mf][nf][r] + bias[col];
        if constexpr (MODE == 0) {
          const int n = (int)col;
          const int which = n >> 10, rem2 = n & 1023;
          const int head = rem2 >> 6, d = rem2 & 63;
          const int b = (int)(row >> 10), s = (int)(row & 1023);
          const unsigned short bv = f2bf(v);
          const long qi = ((long)(b * 16 + head) * 1024 + s) * 64 + d;
          if (which == 0)      outb[qi] = bv;
          else if (which == 1) kbuf[qi] = bv;
          else                 vtbuf[((long)(b * 16 + head) * 64 + d) * 1024 + s] = bv;
        } else if constexpr (MODE == 1) {
          outf[row * N + col] = v + res[row * N + col];
        } else if constexpr (MODE == 2) {
          float mv;
          if (v > 20.f) mv = v;
          else { const float t2 = __expf(v); const float u = t2 * t2 + 2.f * t2;
                 mv = v * u / (u + 2.f); }
          outb[row * (long)N + col] = f2bf(mv);
        } else {
          outf[row * N + col] = v + res[row * N + col];
        }
      }
    }
  }
}

// ---------------------------------------------------------------------------
// Flash attention R11: R10 structure + counted drain + 2-deep bias prefetch.
// Per-tile VMEM queue per wave: [bias(t+1):16][KV(t+1):2][bias(t+2):16].
// End-of-tile vmcnt(16) drains bias(t+1)+KV(t+1); bias(t+2) stays in flight
// across the barrier (compiler auto-waits cover its use two tiles later).
// ---------------------------------------------------------------------------
__global__ __launch_bounds__(512, 2) void attn_kernel(
    const unsigned short* __restrict__ qb, const unsigned short* __restrict__ kb,
    const unsigned short* __restrict__ vtb, const float* __restrict__ bias,
    unsigned short* __restrict__ ctx) {
  constexpr int S = 1024;
  __shared__ unsigned short k_sh[2][64 * 64];
  __shared__ unsigned short vt_sh[2][64 * 64];
  __shared__ unsigned short p_sh[8][16 * 72];

  const int id = blockIdx.x;
  const int c = id & 7, p = id >> 3;
  const int bh = c * 4 + (p >> 3);
  const int q0 = (p & 7) * 128;
  const int tid = threadIdx.x, wave = tid >> 6, lane = tid & 63;
  const int l15 = lane & 15, l4 = lane >> 4;

  const long qbase = ((long)bh * S + q0 + wave * 16 + l15) * 64;
  const bf16x8 qf0 = *reinterpret_cast<const bf16x8*>(qb + qbase + 8 * l4);
  const bf16x8 qf1 = *reinterpret_cast<const bf16x8*>(qb + qbase + 8 * l4 + 32);

  const int sr8 = lane >> 3;
  const int gchunk = ((lane & 7) ^ sr8) * 8;
  const long kbase = (long)bh * S * 64;
  const long vbase = (long)bh * 64 * S;

  const float* bB = bias + ((long)bh * S + q0 + wave * 16 + 4 * l4) * S + l15;

  f32x4 oacc[4] = {};
  float lacc[4] = {};
  float ba[4][4], bb2[4][4];                   // 2-deep ping-pong bias sets

  auto stageKV = [&](int kv, int buf) {
    const int r = wave * 8;
    gload16(kb + kbase + (long)(kv + r + sr8) * 64 + gchunk, &k_sh[buf][r * 64]);
    gload16(vtb + vbase + (long)(r + sr8) * S + kv + gchunk, &vt_sh[buf][r * 64]);
  };

  // prologue: KV(0) -> buf0; bias(0) -> ba; bias(1) -> bb2
  stageKV(0, 0);
#pragma unroll
  for (int r = 0; r < 4; ++r)
#pragma unroll
    for (int nf = 0; nf < 4; ++nf) {
      ba[r][nf]  = bB[(long)r * S + nf * 16];
      bb2[r][nf] = bB[(long)r * S + 64 + nf * 16];
    }
  asm volatile("s_waitcnt vmcnt(0)" ::: "memory");
  __syncthreads();

#pragma unroll 1
  for (int tt = 0; tt < 8; ++tt) {
    const int t0 = 2 * tt;
#pragma unroll
    for (int half = 0; half < 2; ++half) {
      const int t = t0 + half;
      const int cur = half, nxt = half ^ 1;
      float (*bcur)[4] = half ? bb2 : ba;      // consumed this tile, refilled for t+2

      if (t < 15) stageKV((t + 1) * 64, nxt);  // KV first in VMEM queue
      asm volatile("" ::: "memory");           // pin issue order: KV before bias

      f32x4 sc[4];
#pragma unroll
      for (int nf = 0; nf < 4; ++nf) {
        const int r = nf * 16 + l15;
        const bf16x8 kf0 = *reinterpret_cast<const bf16x8*>(
            &k_sh[cur][r * 64 + ((l4) ^ (r & 7)) * 8]);
        const bf16x8 kf1 = *reinterpret_cast<const bf16x8*>(
            &k_sh[cur][r * 64 + ((l4 + 4) ^ (r & 7)) * 8]);
        f32x4 z = {};
        z = __builtin_amdgcn_mfma_f32_16x16x32_bf16(qf0, kf0, z, 0, 0, 0);
        sc[nf] = __builtin_amdgcn_mfma_f32_16x16x32_bf16(qf1, kf1, z, 0, 0, 0);
      }

      // softmax numerator; consume bcur (loaded 2 tiles ago)
      float pv[4][4];
#pragma unroll
      for (int r = 0; r < 4; ++r) {
        float ls = 0.f;
#pragma unroll
        for (int nf = 0; nf < 4; ++nf) {
          const float p = __expf(sc[nf][r] * 0.125f + bcur[r][nf]);
          pv[nf][r] = p;
          ls += p;
        }
        lacc[r] += ls;
      }

      // refill the just-consumed set for tile t+2 (stays in flight past barrier)
      if (t < 14) {
        const float* bn = bB + (t + 2) * 64;
#pragma unroll
        for (int r = 0; r < 4; ++r)
#pragma unroll
          for (int nf = 0; nf < 4; ++nf)
            bcur[r][nf] = bn[(long)r * S + nf * 16];
      }

      // P -> per-wave LDS, then PV
#pragma unroll
      for (int nf = 0; nf < 4; ++nf)
#pragma unroll
        for (int r = 0; r < 4; ++r)
          p_sh[wave][(4 * l4 + r) * 72 + nf * 16 + l15] = f2bf(pv[nf][r]);

      const bf16x8 pa0 = *reinterpret_cast<const bf16x8*>(&p_sh[wave][l15 * 72 + 8 * l4]);
      const bf16x8 pa1 = *reinterpret_cast<const bf16x8*>(&p_sh[wave][l15 * 72 + 8 * l4 + 32]);
#pragma unroll
      for (int nf = 0; nf < 4; ++nf) {
        const int r = nf * 16 + l15;
        const bf16x8 vf0 = *reinterpret_cast<const bf16x8*>(
            &vt_sh[cur][r * 64 + ((l4) ^ (r & 7)) * 8]);
        const bf16x8 vf1 = *reinterpret_cast<const bf16x8*>(
            &vt_sh[cur][r * 64 + ((l4 + 4) ^ (r & 7)) * 8]);
        oacc[nf] = __builtin_amdgcn_mfma_f32_16x16x32_bf16(pa0, vf0, oacc[nf], 0, 0, 0);
        oacc[nf] = __builtin_amdgcn_mfma_f32_16x16x32_bf16(pa1, vf1, oacc[nf], 0, 0, 0);
      }

      // counted drain: waits bias(t+1)+KV(t+1) only; bias(t+2) flies on
      asm volatile("s_waitcnt vmcnt(16)" ::: "memory");
      __syncthreads();
    }
  }

#pragma unroll
  for (int r = 0; r < 4; ++r) {
    float v = lacc[r];
    v += __shfl_xor(v, 1);
    v += __shfl_xor(v, 2);
    v += __shfl_xor(v, 4);
    v += __shfl_xor(v, 8);
    lacc[r] = 1.f / v;
  }

  const int b = bh >> 4, h = bh & 15;
#pragma unroll
  for (int nf = 0; nf < 4; ++nf)
#pragma unroll
    for (int r = 0; r < 4; ++r) {
      const long s = q0 + wave * 16 + 4 * l4 + r;
      const long col = h * 64 + nf * 16 + l15;
      ctx[((long)b * S + s) * 1024 + col] = f2bf(oacc[nf][r] * lacc[r]);
    }
}

// ---------------------------------------------------------------------------
extern "C" void kernel_launch(void* const* d_in, const int* in_sizes, int n_in,
                              void* d_out, int out_size, void* d_ws, size_t ws_size,
                              hipStream_t stream) {
  const float* x    = (const float*)d_in[0];
  const float* ab   = (const float*)d_in[1];
  const float* ln1g = (const float*)d_in[2];
  const float* ln1b = (const float*)d_in[3];
  const float* Wqkv = (const float*)d_in[4];
  const float* bqkv = (const float*)d_in[5];
  const float* Wo   = (const float*)d_in[6];
  const float* bo   = (const float*)d_in[7];
  const float* ln2g = (const float*)d_in[8];
  const float* ln2b = (const float*)d_in[9];
  const float* W1   = (const float*)d_in[10];
  const float* b1   = (const float*)d_in[11];
  const float* W2   = (const float*)d_in[12];
  const float* b2   = (const float*)d_in[13];
  float* out = (float*)d_out;

  char* ws = (char*)d_ws;
  size_t off = 0;
  auto alloc = [&](size_t bytes) {
    char* p = ws + off;
    off += (bytes + 255) & ~(size_t)255;
    return p;
  };
  unsigned short* wqkv_t = (unsigned short*)alloc((size_t)3072 * 1024 * 2);
  unsigned short* wo_t   = (unsigned short*)alloc((size_t)1024 * 1024 * 2);
  unsigned short* w1_t   = (unsigned short*)alloc((size_t)4096 * 1024 * 2);
  unsigned short* w2_t   = (unsigned short*)alloc((size_t)4096 * 1024 * 2);
  unsigned short* h1     = (unsigned short*)alloc((size_t)2048 * 1024 * 2);  // ffn1 aliases h1..vtbuf
  unsigned short* qbuf   = (unsigned short*)alloc((size_t)2048 * 1024 * 2);
  unsigned short* kbuf   = (unsigned short*)alloc((size_t)2048 * 1024 * 2);
  unsigned short* vtbuf  = (unsigned short*)alloc((size_t)2048 * 1024 * 2);
  unsigned short* ctx    = (unsigned short*)alloc((size_t)2048 * 1024 * 2);
  unsigned short* h2     = (unsigned short*)alloc((size_t)2048 * 1024 * 2);
  float*          r1     = (float*)alloc((size_t)2048 * 1024 * 4);
  unsigned short* ffn1   = h1;  // 16MB alias over h1/qbuf/kbuf/vtbuf (dead after attn)
  (void)ws_size; (void)in_sizes; (void)n_in; (void)out_size;

  convert_ln<<<14336, dim3(32, 8), 0, stream>>>(Wqkv, Wo, W1, W2, x, ln1g, ln1b,
                                                wqkv_t, wo_t, w1_t, w2_t, h1);

  gemm_kernel<0, 128, 96><<<512, 256, 0, stream>>>(h1, wqkv_t, bqkv, 2048, 3072, 1024,
                                                   nullptr, nullptr, qbuf, kbuf, vtbuf);

  attn_kernel<<<256, 512, 0, stream>>>(qbuf, kbuf, vtbuf, ab, ctx);

  gemm_kernel<1, 64, 64><<<512, 256, 0, stream>>>(ctx, wo_t, bo, 2048, 1024, 1024,
                                                  r1, x, nullptr, nullptr, nullptr);

  ln_kernel<<<2048, 256, 0, stream>>>(r1, ln2g, ln2b, h2);

  gemm_kernel<2, 128, 128><<<512, 256, 0, stream>>>(h2, w1_t, b1, 2048, 4096, 1024,
                                                    nullptr, nullptr, ffn1, nullptr, nullptr);

  gemm_kernel<3, 64, 64><<<512, 256, 0, stream>>>(ffn1, w2_t, b2, 2048, 1024, 4096,
                                                  out, r1, nullptr, nullptr, nullptr);
}

// Round 12
// 157.228 us; speedup vs baseline: 1.2272x; 1.0140x over previous
//
#include <hip/hip_runtime.h>

// ---------------------------------------------------------------------------
// TransformerBlock: LN1 -> QKV -> attn(+bias, softmax) -> Wo(+x) -> LN2
//                   -> FFN1(+mish) -> FFN2(+residual)
// fp32 I/O, bf16 MFMA GEMMs (16x16x32), flash-style attention.
// R12: attn Q-tile 64 / 4 waves / grid 512 (2 blocks/CU) — K/V is L2-resident
//      after the R10 XCD remap, so trade K/V re-reads for cross-block overlap
//      of the barrier drains. Rest = R11.
// ---------------------------------------------------------------------------

typedef __attribute__((ext_vector_type(8))) __bf16 bf16x8;
typedef __attribute__((ext_vector_type(4))) float  f32x4;

__device__ __forceinline__ unsigned short f2bf(float f) {
  unsigned int u = __builtin_bit_cast(unsigned int, f);
  u += 0x7fffu + ((u >> 16) & 1u);          // round-to-nearest-even
  return (unsigned short)(u >> 16);
}

__device__ __forceinline__ void gload16(const void* g, void* l) {
  __builtin_amdgcn_global_load_lds(
      (const __attribute__((address_space(1))) void*)g,
      (__attribute__((address_space(3))) void*)l, 16, 0, 0);
}

// ---------------------------------------------------------------------------
// Fused: 4 weight converts fp32(KxN)->bf16 transposed(NxK)  +  LN1.
// blocks 0..12287: converts; 12288..14335: LN1 rows.
// ---------------------------------------------------------------------------
__global__ __launch_bounds__(256) void convert_ln(
    const float* __restrict__ Wqkv, const float* __restrict__ Wo,
    const float* __restrict__ W1, const float* __restrict__ W2,
    const float* __restrict__ x, const float* __restrict__ g,
    const float* __restrict__ bln,
    unsigned short* __restrict__ wqkv_t, unsigned short* __restrict__ wo_t,
    unsigned short* __restrict__ w1_t, unsigned short* __restrict__ w2_t,
    unsigned short* __restrict__ h1) {
  __shared__ float tile[32][33];
  __shared__ float ps[4], ps2[4];
  const int id = blockIdx.x;
  const int tx = threadIdx.x, ty = threadIdx.y;   // (32,8)

  if (id < 12288) {
    const float* W; unsigned short* Wt; int K, N, t;
    if (id < 3072)      { W = Wqkv; Wt = wqkv_t; K = 1024; N = 3072; t = id; }
    else if (id < 4096) { W = Wo;   Wt = wo_t;   K = 1024; N = 1024; t = id - 3072; }
    else if (id < 8192) { W = W1;   Wt = w1_t;   K = 1024; N = 4096; t = id - 4096; }
    else                { W = W2;   Wt = w2_t;   K = 4096; N = 1024; t = id - 8192; }
    const int nx = N >> 5;
    const int n0 = (t % nx) * 32, k0 = (t / nx) * 32;
#pragma unroll
    for (int r = 0; r < 4; ++r)
      tile[ty + 8 * r][tx] = W[(size_t)(k0 + ty + 8 * r) * N + n0 + tx];
    __syncthreads();
#pragma unroll
    for (int r = 0; r < 4; ++r)
      Wt[(size_t)(n0 + ty + 8 * r) * K + k0 + tx] = f2bf(tile[tx][ty + 8 * r]);
  } else {
    const int row = id - 12288;
    const int t = ty * 32 + tx;
    const float4 v = reinterpret_cast<const float4*>(x + (size_t)row * 1024)[t];
    float s  = v.x + v.y + v.z + v.w;
    float s2 = v.x * v.x + v.y * v.y + v.z * v.z + v.w * v.w;
#pragma unroll
    for (int m = 1; m < 64; m <<= 1) { s += __shfl_xor(s, m); s2 += __shfl_xor(s2, m); }
    const int wv = t >> 6;
    if ((t & 63) == 0) { ps[wv] = s; ps2[wv] = s2; }
    __syncthreads();
    float ts = 0.f, ts2 = 0.f;
#pragma unroll
    for (int i = 0; i < 4; ++i) { ts += ps[i]; ts2 += ps2[i]; }
    const float mu = ts * (1.f / 1024.f);
    const float var = ts2 * (1.f / 1024.f) - mu * mu;
    const float rstd = rsqrtf(var + 1e-5f);
    const float4 gg = reinterpret_cast<const float4*>(g)[t];
    const float4 bb = reinterpret_cast<const float4*>(bln)[t];
    ushort4 ov;
    ov.x = f2bf((v.x - mu) * rstd * gg.x + bb.x);
    ov.y = f2bf((v.y - mu) * rstd * gg.y + bb.y);
    ov.z = f2bf((v.z - mu) * rstd * gg.z + bb.z);
    ov.w = f2bf((v.w - mu) * rstd * gg.w + bb.w);
    *reinterpret_cast<ushort4*>(h1 + (size_t)row * 1024 + t * 4) = ov;
  }
}

// ---------------------------------------------------------------------------
// LayerNorm (standalone, for LN2).
// ---------------------------------------------------------------------------
__global__ __launch_bounds__(256) void ln_kernel(const float* __restrict__ in,
                                                 const float* __restrict__ g,
                                                 const float* __restrict__ b,
                                                 unsigned short* __restrict__ out) {
  const int row = blockIdx.x;
  const int t = threadIdx.x;
  const float4 v = reinterpret_cast<const float4*>(in + (size_t)row * 1024)[t];
  float s  = v.x + v.y + v.z + v.w;
  float s2 = v.x * v.x + v.y * v.y + v.z * v.z + v.w * v.w;
#pragma unroll
  for (int m = 1; m < 64; m <<= 1) { s += __shfl_xor(s, m); s2 += __shfl_xor(s2, m); }
  __shared__ float ps[4], ps2[4];
  const int wv = t >> 6;
  if ((t & 63) == 0) { ps[wv] = s; ps2[wv] = s2; }
  __syncthreads();
  float ts = 0.f, ts2 = 0.f;
#pragma unroll
  for (int i = 0; i < 4; ++i) { ts += ps[i]; ts2 += ps2[i]; }
  const float mu = ts * (1.f / 1024.f);
  const float var = ts2 * (1.f / 1024.f) - mu * mu;
  const float rstd = rsqrtf(var + 1e-5f);
  const float4 gg = reinterpret_cast<const float4*>(g)[t];
  const float4 bb = reinterpret_cast<const float4*>(b)[t];
  ushort4 ov;
  ov.x = f2bf((v.x - mu) * rstd * gg.x + bb.x);
  ov.y = f2bf((v.y - mu) * rstd * gg.y + bb.y);
  ov.z = f2bf((v.z - mu) * rstd * gg.z + bb.z);
  ov.w = f2bf((v.w - mu) * rstd * gg.w + bb.w);
  *reinterpret_cast<ushort4*>(out + (size_t)row * 1024 + t * 4) = ov;
}

// ---------------------------------------------------------------------------
// GEMM (R6 loop, R9 order): C = A @ Bt^T + bias. 2-stage prefetch, one
// vmcnt(0)+barrier per K-step, XOR chunk swizzle, XCD-chunked 2-D blocking.
// ---------------------------------------------------------------------------
template <int MODE, int BM, int BN>
__global__ __launch_bounds__(256, 2) void gemm_kernel(
    const unsigned short* __restrict__ A, const unsigned short* __restrict__ Bt,
    const float* __restrict__ bias, int M, int N, int K,
    float* __restrict__ outf, const float* __restrict__ res,
    unsigned short* __restrict__ outb,
    unsigned short* __restrict__ kbuf, unsigned short* __restrict__ vtbuf) {
  constexpr int BK = 64;
  constexpr int WN = (BN >= 96 || BM == 64) ? 2 : 1;
  constexpr int WM = 4 / WN;
  constexpr int WR = BM / WM / 16;
  constexpr int WC = BN / WN / 16;
  constexpr int AI = BM / 32, BI = BN / 32;
  __shared__ unsigned short a_sh[2][BM * BK];
  __shared__ unsigned short b_sh[2][BN * BK];

  const int tid = threadIdx.x;
  const int wave = tid >> 6, lane = tid & 63;
  const int wm = wave / WN, wn = wave % WN;
  const int l15 = lane & 15, l4 = lane >> 4;

  const int nwg = gridDim.x, cpx = nwg >> 3;
  const int swz = (blockIdx.x & 7) * cpx + (blockIdx.x >> 3);
  const int GX = N / BN;
  const int sr  = swz / (8 * GX);
  const int rem = swz % (8 * GX);
  const long bm0 = (long)(sr * 8 + (rem & 7)) * BM;
  const long bn0 = (long)(rem >> 3) * BN;

  const int sr8 = lane >> 3;
  const int gc  = ((lane & 7) ^ sr8) * 8;       // inverse-swizzled source chunk

  const unsigned short* agp[AI];
  const unsigned short* bgp[BI];
  int aoff[AI], boff[BI];
#pragma unroll
  for (int i = 0; i < AI; ++i) {
    const int r = wave * (BM / 4) + i * 8;
    agp[i] = A + (bm0 + r + sr8) * (long)K + gc;
    aoff[i] = r * BK;
  }
#pragma unroll
  for (int i = 0; i < BI; ++i) {
    const int r = wave * (BN / 4) + i * 8;
    bgp[i] = Bt + (bn0 + r + sr8) * (long)K + gc;
    boff[i] = r * BK;
  }

  auto stage = [&](int buf, int k0) {
#pragma unroll
    for (int i = 0; i < AI; ++i) gload16(agp[i] + k0, &a_sh[buf][aoff[i]]);
#pragma unroll
    for (int i = 0; i < BI; ++i) gload16(bgp[i] + k0, &b_sh[buf][boff[i]]);
  };

  f32x4 acc[WR][WC] = {};

  stage(0, 0);
  asm volatile("s_waitcnt vmcnt(0)" ::: "memory");
  __syncthreads();

  const int NT = K / BK;
  for (int t = 0; t < NT; ++t) {
    const int cur = t & 1;
    if (t + 1 < NT) stage(cur ^ 1, (t + 1) * BK);   // prefetch next tile

#pragma unroll
    for (int kk = 0; kk < 2; ++kk) {
      bf16x8 af[WR], bfr[WC];
#pragma unroll
      for (int mf = 0; mf < WR; ++mf) {
        const int r = wm * (BM / WM) + mf * 16 + l15;
        const int c = ((kk * 4 + l4) ^ (r & 7)) * 8;
        af[mf] = *reinterpret_cast<const bf16x8*>(&a_sh[cur][r * BK + c]);
      }
#pragma unroll
      for (int nf = 0; nf < WC; ++nf) {
        const int r = wn * (BN / WN) + nf * 16 + l15;
        const int c = ((kk * 4 + l4) ^ (r & 7)) * 8;
        bfr[nf] = *reinterpret_cast<const bf16x8*>(&b_sh[cur][r * BK + c]);
      }
#pragma unroll
      for (int mf = 0; mf < WR; ++mf)
#pragma unroll
        for (int nf = 0; nf < WC; ++nf)
          acc[mf][nf] = __builtin_amdgcn_mfma_f32_16x16x32_bf16(af[mf], bfr[nf], acc[mf][nf], 0, 0, 0);
    }

    asm volatile("s_waitcnt vmcnt(0)" ::: "memory");  // prefetch landed
    __syncthreads();                                  // buf[cur] consumed by all
  }

#pragma unroll
  for (int mf = 0; mf < WR; ++mf) {
#pragma unroll
    for (int nf = 0; nf < WC; ++nf) {
#pragma unroll
      for (int r = 0; r < 4; ++r) {
        const long row = bm0 + wm * (BM / WM) + mf * 16 + 4 * l4 + r;
        const long col = bn0 + wn * (BN / WN) + nf * 16 + l15;
        float v = acc[mf][nf][r] + bias[col];
        if constexpr (MODE == 0) {
          const int n = (int)col;
          const int which = n >> 10, rem2 = n & 1023;
          const int head = rem2 >> 6, d = rem2 & 63;
          const int b = (int)(row >> 10), s = (int)(row & 1023);
          const unsigned short bv = f2bf(v);
          const long qi = ((long)(b * 16 + head) * 1024 + s) * 64 + d;
          if (which == 0)      outb[qi] = bv;
          else if (which == 1) kbuf[qi] = bv;
          else                 vtbuf[((long)(b * 16 + head) * 64 + d) * 1024 + s] = bv;
        } else if constexpr (MODE == 1) {
          outf[row * N + col] = v + res[row * N + col];
        } else if constexpr (MODE == 2) {
          float mv;
          if (v > 20.f) mv = v;
          else { const float t2 = __expf(v); const float u = t2 * t2 + 2.f * t2;
                 mv = v * u / (u + 2.f); }
          outb[row * (long)N + col] = f2bf(mv);
        } else {
          outf[row * N + col] = v + res[row * N + col];
        }
      }
    }
  }
}

// ---------------------------------------------------------------------------
// Flash attention R12: grid 512 (2 blocks/CU), 4 waves x 16 q-rows (Q-tile 64).
// XCD remap: c=id&7 owns heads 4c..4c+3; 16 q-blocks/head on the same XCD
// -> K/V L2-resident. Counted drain vmcnt(16) + 2-deep bias prefetch.
// Per-wave queue at tile end: [bias(t+1):16][KV(t+1):4][bias(t+2):16].
// ---------------------------------------------------------------------------
__global__ __launch_bounds__(256, 2) void attn_kernel(
    const unsigned short* __restrict__ qb, const unsigned short* __restrict__ kb,
    const unsigned short* __restrict__ vtb, const float* __restrict__ bias,
    unsigned short* __restrict__ ctx) {
  constexpr int S = 1024;
  __shared__ unsigned short k_sh[2][64 * 64];
  __shared__ unsigned short vt_sh[2][64 * 64];
  __shared__ unsigned short p_sh[4][16 * 72];

  const int id = blockIdx.x;
  const int c = id & 7, p = id >> 3;
  const int bh = c * 4 + (p >> 4);             // 4 heads per XCD
  const int q0 = (p & 15) * 64;                // 16 q-blocks per head
  const int tid = threadIdx.x, wave = tid >> 6, lane = tid & 63;
  const int l15 = lane & 15, l4 = lane >> 4;

  const long qbase = ((long)bh * S + q0 + wave * 16 + l15) * 64;
  const bf16x8 qf0 = *reinterpret_cast<const bf16x8*>(qb + qbase + 8 * l4);
  const bf16x8 qf1 = *reinterpret_cast<const bf16x8*>(qb + qbase + 8 * l4 + 32);

  const int sr8 = lane >> 3;
  const int gchunk = ((lane & 7) ^ sr8) * 8;
  const long kbase = (long)bh * S * 64;
  const long vbase = (long)bh * 64 * S;

  const float* bB = bias + ((long)bh * S + q0 + wave * 16 + 4 * l4) * S + l15;

  f32x4 oacc[4] = {};
  float lacc[4] = {};
  float ba[4][4], bb2[4][4];                   // 2-deep ping-pong bias sets

  auto stageKV = [&](int kv, int buf) {
#pragma unroll
    for (int i = 0; i < 2; ++i) {
      const int r = wave * 16 + i * 8;         // 4 waves x 16 rows = 64
      gload16(kb + kbase + (long)(kv + r + sr8) * 64 + gchunk, &k_sh[buf][r * 64]);
      gload16(vtb + vbase + (long)(r + sr8) * S + kv + gchunk, &vt_sh[buf][r * 64]);
    }
  };

  // prologue: KV(0) -> buf0; bias(0) -> ba; bias(1) -> bb2
  stageKV(0, 0);
#pragma unroll
  for (int r = 0; r < 4; ++r)
#pragma unroll
    for (int nf = 0; nf < 4; ++nf) {
      ba[r][nf]  = bB[(long)r * S + nf * 16];
      bb2[r][nf] = bB[(long)r * S + 64 + nf * 16];
    }
  asm volatile("s_waitcnt vmcnt(0)" ::: "memory");
  __syncthreads();

#pragma unroll 1
  for (int tt = 0; tt < 8; ++tt) {
    const int t0 = 2 * tt;
#pragma unroll
    for (int half = 0; half < 2; ++half) {
      const int t = t0 + half;
      const int cur = half, nxt = half ^ 1;
      float (*bcur)[4] = half ? bb2 : ba;      // consumed this tile, refilled for t+2

      if (t < 15) stageKV((t + 1) * 64, nxt);  // KV first in VMEM queue
      asm volatile("" ::: "memory");           // pin issue order: KV before bias

      f32x4 sc[4];
#pragma unroll
      for (int nf = 0; nf < 4; ++nf) {
        const int r = nf * 16 + l15;
        const bf16x8 kf0 = *reinterpret_cast<const bf16x8*>(
            &k_sh[cur][r * 64 + ((l4) ^ (r & 7)) * 8]);
        const bf16x8 kf1 = *reinterpret_cast<const bf16x8*>(
            &k_sh[cur][r * 64 + ((l4 + 4) ^ (r & 7)) * 8]);
        f32x4 z = {};
        z = __builtin_amdgcn_mfma_f32_16x16x32_bf16(qf0, kf0, z, 0, 0, 0);
        sc[nf] = __builtin_amdgcn_mfma_f32_16x16x32_bf16(qf1, kf1, z, 0, 0, 0);
      }

      // softmax numerator; consume bcur (loaded 2 tiles ago)
      float pv[4][4];
#pragma unroll
      for (int r = 0; r < 4; ++r) {
        float ls = 0.f;
#pragma unroll
        for (int nf = 0; nf < 4; ++nf) {
          const float p2 = __expf(sc[nf][r] * 0.125f + bcur[r][nf]);
          pv[nf][r] = p2;
          ls += p2;
        }
        lacc[r] += ls;
      }

      // refill the just-consumed set for tile t+2 (stays in flight past barrier)
      if (t < 14) {
        const float* bn = bB + (t + 2) * 64;
#pragma unroll
        for (int r = 0; r < 4; ++r)
#pragma unroll
          for (int nf = 0; nf < 4; ++nf)
            bcur[r][nf] = bn[(long)r * S + nf * 16];
      }

      // P -> per-wave LDS, then PV
#pragma unroll
      for (int nf = 0; nf < 4; ++nf)
#pragma unroll
        for (int r = 0; r < 4; ++r)
          p_sh[wave][(4 * l4 + r) * 72 + nf * 16 + l15] = f2bf(pv[nf][r]);

      const bf16x8 pa0 = *reinterpret_cast<const bf16x8*>(&p_sh[wave][l15 * 72 + 8 * l4]);
      const bf16x8 pa1 = *reinterpret_cast<const bf16x8*>(&p_sh[wave][l15 * 72 + 8 * l4 + 32]);
#pragma unroll
      for (int nf = 0; nf < 4; ++nf) {
        const int r = nf * 16 + l15;
        const bf16x8 vf0 = *reinterpret_cast<const bf16x8*>(
            &vt_sh[cur][r * 64 + ((l4) ^ (r & 7)) * 8]);
        const bf16x8 vf1 = *reinterpret_cast<const bf16x8*>(
            &vt_sh[cur][r * 64 + ((l4 + 4) ^ (r & 7)) * 8]);
        oacc[nf] = __builtin_amdgcn_mfma_f32_16x16x32_bf16(pa0, vf0, oacc[nf], 0, 0, 0);
        oacc[nf] = __builtin_amdgcn_mfma_f32_16x16x32_bf16(pa1, vf1, oacc[nf], 0, 0, 0);
      }

      // counted drain: waits bias(t+1)+KV(t+1) only; bias(t+2) flies on
      asm volatile("s_waitcnt vmcnt(16)" ::: "memory");
      __syncthreads();
    }
  }

#pragma unroll
  for (int r = 0; r < 4; ++r) {
    float v = lacc[r];
    v += __shfl_xor(v, 1);
    v += __shfl_xor(v, 2);
    v += __shfl_xor(v, 4);
    v += __shfl_xor(v, 8);
    lacc[r] = 1.f / v;
  }

  const int b = bh >> 4, h = bh & 15;
#pragma unroll
  for (int nf = 0; nf < 4; ++nf)
#pragma unroll
    for (int r = 0; r < 4; ++r) {
      const long s = q0 + wave * 16 + 4 * l4 + r;
      const long col = h * 64 + nf * 16 + l15;
      ctx[((long)b * S + s) * 1024 + col] = f2bf(oacc[nf][r] * lacc[r]);
    }
}

// ---------------------------------------------------------------------------
extern "C" void kernel_launch(void* const* d_in, const int* in_sizes, int n_in,
                              void* d_out, int out_size, void* d_ws, size_t ws_size,
                              hipStream_t stream) {
  const float* x    = (const float*)d_in[0];
  const float* ab   = (const float*)d_in[1];
  const float* ln1g = (const float*)d_in[2];
  const float* ln1b = (const float*)d_in[3];
  const float* Wqkv = (const float*)d_in[4];
  const float* bqkv = (const float*)d_in[5];
  const float* Wo   = (const float*)d_in[6];
  const float* bo   = (const float*)d_in[7];
  const float* ln2g = (const float*)d_in[8];
  const float* ln2b = (const float*)d_in[9];
  const float* W1   = (const float*)d_in[10];
  const float* b1   = (const float*)d_in[11];
  const float* W2   = (const float*)d_in[12];
  const float* b2   = (const float*)d_in[13];
  float* out = (float*)d_out;

  char* ws = (char*)d_ws;
  size_t off = 0;
  auto alloc = [&](size_t bytes) {
    char* p = ws + off;
    off += (bytes + 255) & ~(size_t)255;
    return p;
  };
  unsigned short* wqkv_t = (unsigned short*)alloc((size_t)3072 * 1024 * 2);
  unsigned short* wo_t   = (unsigned short*)alloc((size_t)1024 * 1024 * 2);
  unsigned short* w1_t   = (unsigned short*)alloc((size_t)4096 * 1024 * 2);
  unsigned short* w2_t   = (unsigned short*)alloc((size_t)4096 * 1024 * 2);
  unsigned short* h1     = (unsigned short*)alloc((size_t)2048 * 1024 * 2);  // ffn1 aliases h1..vtbuf
  unsigned short* qbuf   = (unsigned short*)alloc((size_t)2048 * 1024 * 2);
  unsigned short* kbuf   = (unsigned short*)alloc((size_t)2048 * 1024 * 2);
  unsigned short* vtbuf  = (unsigned short*)alloc((size_t)2048 * 1024 * 2);
  unsigned short* ctx    = (unsigned short*)alloc((size_t)2048 * 1024 * 2);
  unsigned short* h2     = (unsigned short*)alloc((size_t)2048 * 1024 * 2);
  float*          r1     = (float*)alloc((size_t)2048 * 1024 * 4);
  unsigned short* ffn1   = h1;  // 16MB alias over h1/qbuf/kbuf/vtbuf (dead after attn)
  (void)ws_size; (void)in_sizes; (void)n_in; (void)out_size;

  convert_ln<<<14336, dim3(32, 8), 0, stream>>>(Wqkv, Wo, W1, W2, x, ln1g, ln1b,
                                                wqkv_t, wo_t, w1_t, w2_t, h1);

  gemm_kernel<0, 128, 96><<<512, 256, 0, stream>>>(h1, wqkv_t, bqkv, 2048, 3072, 1024,
                                                   nullptr, nullptr, qbuf, kbuf, vtbuf);

  attn_kernel<<<512, 256, 0, stream>>>(qbuf, kbuf, vtbuf, ab, ctx);

  gemm_kernel<1, 64, 64><<<512, 256, 0, stream>>>(ctx, wo_t, bo, 2048, 1024, 1024,
                                                  r1, x, nullptr, nullptr, nullptr);

  ln_kernel<<<2048, 256, 0, stream>>>(r1, ln2g, ln2b, h2);

  gemm_kernel<2, 128, 128><<<512, 256, 0, stream>>>(h2, w1_t, b1, 2048, 4096, 1024,
                                                    nullptr, nullptr, ffn1, nullptr, nullptr);

  gemm_kernel<3, 64, 64><<<512, 256, 0, stream>>>(ffn1, w2_t, b2, 2048, 1024, 4096,
                                                  out, r1, nullptr, nullptr, nullptr);
}